// Round 4
// baseline (1007.800 us; speedup 1.0000x reference)
//
#include <hip/hip_runtime.h>
#include <hip/hip_bf16.h>

typedef unsigned int u32;
typedef unsigned short u16;
typedef __bf16 bf16x8 __attribute__((ext_vector_type(8)));
typedef float f32x4 __attribute__((ext_vector_type(4)));

// ---------- bf16 bit helpers ----------
__device__ __forceinline__ float b2f(u16 s){ union{u32 x; float f;} c; c.x = ((u32)s) << 16; return c.f; }
__device__ __forceinline__ float b2f_lo(u32 u){ union{u32 x; float f;} c; c.x = u << 16; return c.f; }
__device__ __forceinline__ float b2f_hi(u32 u){ union{u32 x; float f;} c; c.x = u & 0xFFFF0000u; return c.f; }
__device__ __forceinline__ u16 f2b(float f){
    union{float f; u32 u;} c; c.f = f;
    u32 r = c.u + 0x7FFFu + ((c.u >> 16) & 1u);
    return (u16)(r >> 16);
}
__device__ __forceinline__ u32 pk(float lo, float hi){
    return (u32)f2b(lo) | ((u32)f2b(hi) << 16);
}

// Problem constants: B=4, T=2048, D=1024, H=16, HD=64, NF=128, chunk C=128, NC=16
// All inputs FLOAT32; OUTPUT is FLOAT32 (reference returns jnp.float32).

// ---------- 1024x1024 transpose + fp32->bf16 convert (weights -> W^T bf16) ----------
__global__ __launch_bounds__(256) void transpose1024(const float* __restrict__ in, u16* __restrict__ out)
{
    __shared__ u16 tile[64][72];
    int kb = blockIdx.x * 64, nb = blockIdx.y * 64, tid = threadIdx.x;
#pragma unroll
    for (int i = 0; i < 2; i++){
        int idx = tid + 256*i; int r = idx >> 3; int c8 = (idx & 7) * 8;
        const float* p = &in[(size_t)(kb + r)*1024 + nb + c8];
        float4 lo = *reinterpret_cast<const float4*>(p);
        float4 hi = *reinterpret_cast<const float4*>(p + 4);
        uint4 v;
        v.x = pk(lo.x, lo.y); v.y = pk(lo.z, lo.w);
        v.z = pk(hi.x, hi.y); v.w = pk(hi.z, hi.w);
        *reinterpret_cast<uint4*>(&tile[r][c8]) = v;
    }
    __syncthreads();
#pragma unroll
    for (int i = 0; i < 2; i++){
        int idx = tid + 256*i; int c = idx >> 3; int r8 = (idx & 7) * 8;
        u32 w[4];
#pragma unroll
        for (int j = 0; j < 4; j++)
            w[j] = (u32)tile[r8 + 2*j][c] | ((u32)tile[r8 + 2*j + 1][c] << 16);
        uint4 v; v.x = w[0]; v.y = w[1]; v.z = w[2]; v.w = w[3];
        *reinterpret_cast<uint4*>(&out[(size_t)(nb + c)*1024 + kb + r8]) = v;
    }
}

// ---------- MFMA bf16 GEMM: C[8192,1024] = A[8192,1024] * W[1024,1024], BT = bf16 W^T ----------
// AF32: A is fp32 (converted to bf16 during staging); else A is bf16.
// MODE 0: write fp32, remapped (B,H,T,HD)
// MODE 1: write bf16, remapped (B,H,T,HD)
// MODE 2: write fp32, plain row-major (final output)
template<int MODE, int AF32>
__global__ __launch_bounds__(256) void gemm128(const void* __restrict__ Ap, const u16* __restrict__ BT,
                                               float* __restrict__ outf, u16* __restrict__ outh)
{
    __shared__ u16 As[128][40];   // [m][k], 80B rows (16B aligned, <=2-way banks = free)
    __shared__ u16 Bs[128][40];   // [n][k] (rows of W^T)
    int tid = threadIdx.x; int lane = tid & 63; int w = tid >> 6;
    int m0 = blockIdx.x * 128, n0 = blockIdx.y * 128;
    int wm = (w >> 1) * 64, wn = (w & 1) * 64;
    int fr = lane & 15, fk = (lane >> 4) * 8;
    f32x4 acc[4][4] = {};
    int lr = tid >> 2;          // 0..63
    int lk = (tid & 3) * 8;     // 0,8,16,24
    const u16*   A16 = (const u16*)Ap;
    const float* A32 = (const float*)Ap;
    for (int k0 = 0; k0 < 1024; k0 += 32){
        uint4 a0, a1, b0, b1;
        if (AF32){
            const float* p0 = &A32[(size_t)(m0 + lr)*1024 + k0 + lk];
            const float* p1 = &A32[(size_t)(m0 + 64 + lr)*1024 + k0 + lk];
            float4 l0 = *reinterpret_cast<const float4*>(p0);
            float4 h0 = *reinterpret_cast<const float4*>(p0 + 4);
            float4 l1 = *reinterpret_cast<const float4*>(p1);
            float4 h1 = *reinterpret_cast<const float4*>(p1 + 4);
            a0.x = pk(l0.x, l0.y); a0.y = pk(l0.z, l0.w); a0.z = pk(h0.x, h0.y); a0.w = pk(h0.z, h0.w);
            a1.x = pk(l1.x, l1.y); a1.y = pk(l1.z, l1.w); a1.z = pk(h1.x, h1.y); a1.w = pk(h1.z, h1.w);
        } else {
            a0 = *reinterpret_cast<const uint4*>(&A16[(size_t)(m0 + lr)*1024 + k0 + lk]);
            a1 = *reinterpret_cast<const uint4*>(&A16[(size_t)(m0 + 64 + lr)*1024 + k0 + lk]);
        }
        b0 = *reinterpret_cast<const uint4*>(&BT[(size_t)(n0 + lr)*1024 + k0 + lk]);
        b1 = *reinterpret_cast<const uint4*>(&BT[(size_t)(n0 + 64 + lr)*1024 + k0 + lk]);
        __syncthreads();
        *reinterpret_cast<uint4*>(&As[lr][lk])      = a0;
        *reinterpret_cast<uint4*>(&As[64 + lr][lk]) = a1;
        *reinterpret_cast<uint4*>(&Bs[lr][lk])      = b0;
        *reinterpret_cast<uint4*>(&Bs[64 + lr][lk]) = b1;
        __syncthreads();
        bf16x8 af[4], bf[4];
#pragma unroll
        for (int i = 0; i < 4; i++){
            af[i] = *reinterpret_cast<const bf16x8*>(&As[wm + i*16 + fr][fk]);
            bf[i] = *reinterpret_cast<const bf16x8*>(&Bs[wn + i*16 + fr][fk]);
        }
#pragma unroll
        for (int i = 0; i < 4; i++)
#pragma unroll
            for (int j = 0; j < 4; j++)
                acc[i][j] = __builtin_amdgcn_mfma_f32_16x16x32_bf16(af[i], bf[j], acc[i][j], 0, 0, 0);
    }
#pragma unroll
    for (int i = 0; i < 4; i++){
        int row0 = m0 + wm + i*16 + ((lane >> 4) << 2);
#pragma unroll
        for (int j = 0; j < 4; j++){
            int col = n0 + wn + j*16 + fr;
#pragma unroll
            for (int r = 0; r < 4; r++){
                float val = acc[i][j][r];
                int row = row0 + r;
                if (MODE == 2){
                    outf[(size_t)row*1024 + col] = val;
                } else {
                    int bb = row >> 11, t = row & 2047, h = col >> 6, d = col & 63;
                    size_t idx = (((size_t)(bb*16 + h))*2048 + t)*64 + d;
                    if (MODE == 0) outf[idx] = val;
                    else           outh[idx] = f2b(val);
                }
            }
        }
    }
}

// ---------- FAVOR+ feature map (one tensor): phi = exp(x.Wf - 0.5||x||^2)/sqrt(NF) ----------
__global__ __launch_bounds__(256) void featmap(const float* __restrict__ xf, const float* __restrict__ Wf,
                                               u16* __restrict__ xp)
{
    __shared__ float xs[2][64];
    int tid = threadIdx.x;
    int half = tid >> 7, f = tid & 127;
    size_t tok = (size_t)blockIdx.x * 2 + half;
    if (f < 64) xs[half][f] = xf[tok*64 + f];
    __syncthreads();
    float dq = 0.f, sq = 0.f;
#pragma unroll
    for (int d = 0; d < 64; d++){
        float wv = Wf[d*128 + f];
        float qd = xs[half][d];
        dq += qd*wv; sq += qd*qd;
    }
    const float c = 0.08838834764831845f; // 1/sqrt(128)
    xp[tok*128 + f] = f2b(__expf(fminf(dq - 0.5f*sq, 60.f)) * c);
}

// ---------- per-chunk KV summaries: S_c = Kp_c^T V_c (128x64), z_c = colsum(Kp_c) ----------
__global__ __launch_bounds__(256) void chunk_sum(const u16* __restrict__ kp, const u16* __restrict__ vh,
                                                 float* __restrict__ Ss, float* __restrict__ zs)
{
    __shared__ u16 Kl[128][128];
    __shared__ u16 Vl[128][64];
    int blk = blockIdx.x, tid = threadIdx.x;
    int bh = blk >> 4, c = blk & 15;
    const u16* kpb = kp + ((size_t)bh*2048 + c*128)*128;
    const u16* vb  = vh + ((size_t)bh*2048 + c*128)*64;
#pragma unroll
    for (int i = 0; i < 8; i++){ int idx = tid + 256*i; int t = idx >> 4, f8 = (idx & 15)*8;
        *reinterpret_cast<uint4*>(&Kl[t][f8]) = *reinterpret_cast<const uint4*>(&kpb[(size_t)t*128 + f8]); }
#pragma unroll
    for (int i = 0; i < 4; i++){ int idx = tid + 256*i; int t = idx >> 3, d8 = (idx & 7)*8;
        *reinterpret_cast<uint4*>(&Vl[t][d8]) = *reinterpret_cast<const uint4*>(&vb[(size_t)t*64 + d8]); }
    __syncthreads();
    int d = tid & 63, fq = tid >> 6;
    float acc[32];
#pragma unroll
    for (int i = 0; i < 32; i++) acc[i] = 0.f;
    for (int t = 0; t < 128; t++){
        float vd = b2f(Vl[t][d]);
        const u32* kr = reinterpret_cast<const u32*>(&Kl[t][fq*32]);
#pragma unroll
        for (int i = 0; i < 16; i++){
            u32 u = kr[i];
            acc[2*i]     += b2f_lo(u) * vd;
            acc[2*i + 1] += b2f_hi(u) * vd;
        }
    }
    float* Sb = Ss + (size_t)blk*8192;
#pragma unroll
    for (int i = 0; i < 32; i++) Sb[(size_t)(fq*32 + i)*64 + d] = acc[i];
    if (tid < 128){
        float z = 0.f;
        for (int t = 0; t < 128; t++) z += b2f(Kl[t][tid]);
        zs[(size_t)blk*128 + tid] = z;
    }
}

// ---------- exclusive prefix over the 16 chunks (per bh) ----------
__global__ __launch_bounds__(256) void prefix_chunks(float* __restrict__ Ss, float* __restrict__ zs)
{
    int bh = blockIdx.x, tid = threadIdx.x;
    float* base = Ss + (size_t)bh*16*8192;
    for (int e = tid; e < 8192; e += 256){
        float run = 0.f;
#pragma unroll
        for (int c = 0; c < 16; c++){
            float v = base[(size_t)c*8192 + e];
            base[(size_t)c*8192 + e] = run;
            run += v;
        }
    }
    if (tid < 128){
        float run = 0.f; float* zp = zs + (size_t)bh*16*128 + tid;
#pragma unroll
        for (int c = 0; c < 16; c++){ float v = zp[c*128]; zp[c*128] = run; run += v; }
    }
}

// ---------- per-chunk output: y = (tril(Qp Kp^T) V + Qp S_in) / (rowsum + Qp.z_in + eps) ----------
__global__ __launch_bounds__(256) void chunk_out(const u16* __restrict__ qp, const u16* __restrict__ kp,
                                                 const u16* __restrict__ vh, const float* __restrict__ Ss,
                                                 const float* __restrict__ zs, float* __restrict__ deng,
                                                 u16* __restrict__ y2d)
{
    __shared__ u16 Qt[128][128];   // Qt[f][t]  32KB
    __shared__ u16 At[128][128];   // At[s][t]  32KB (masked)
    int blk = blockIdx.x, tid = threadIdx.x;
    int bh = blk >> 4, c = blk & 15;
    int b = bh >> 4, h = bh & 15, t0 = c*128;
    const u16* qpb = qp + ((size_t)bh*2048 + t0)*128;
    const u16* kpb = kp + ((size_t)bh*2048 + t0)*128;
    const u16* vb  = vh + ((size_t)bh*2048 + t0)*64;
    const float* Sb = Ss + (size_t)blk*8192;
    const float* zb = zs + (size_t)blk*128;
    // stage Q transposed
#pragma unroll
    for (int i = 0; i < 8; i++){
        int idx = tid + 256*i;
        int t = idx & 127, f8 = (idx >> 7) * 8;
        uint4 v = *reinterpret_cast<const uint4*>(&qpb[(size_t)t*128 + f8]);
        u32 ww[4] = {v.x, v.y, v.z, v.w};
#pragma unroll
        for (int j = 0; j < 4; j++){
            Qt[f8 + 2*j][t]     = (u16)(ww[j] & 0xFFFFu);
            Qt[f8 + 2*j + 1][t] = (u16)(ww[j] >> 16);
        }
    }
    __syncthreads();
    // phase 1: A[t][s] = qp_t . kp_s, masked s<=t, stored transposed
    {
        int t = tid & 127, sh = tid >> 7;
        if (sh == 1 && t < 64){           // fully above diagonal -> zeros
#pragma unroll
            for (int s = 64; s < 128; s++) At[s][t] = 0;
        } else {
            float qv[128];
#pragma unroll
            for (int f = 0; f < 128; f++) qv[f] = b2f(Qt[f][t]);
            for (int s = sh*64; s < sh*64 + 64; s++){
                const u32* kr = reinterpret_cast<const u32*>(kpb + (size_t)s*128);
                float a = 0.f;
#pragma unroll
                for (int f2 = 0; f2 < 64; f2++){
                    u32 ku = kr[f2];
                    a += qv[2*f2] * b2f_lo(ku) + qv[2*f2 + 1] * b2f_hi(ku);
                }
                At[s][t] = f2b((s <= t) ? a : 0.f);
            }
        }
    }
    __syncthreads();
    // denominator per row -> global scratch
    if (tid < 128){
        int t = tid;
        float dd = 1e-6f;
        for (int s = 0; s <= t; s++) dd += b2f(At[s][t]);
        for (int f = 0; f < 128; f++) dd += b2f(Qt[f][t]) * zb[f];
        *(volatile float*)&deng[(size_t)blk*128 + t] = dd;
    }
    __syncthreads();
    // phase 2: numerator and output
    {
        int d = tid & 63, tq = tid >> 6;
        float acc[32];
#pragma unroll
        for (int i = 0; i < 32; i++) acc[i] = 0.f;
        int smax = (tq + 1) * 32;   // A is zero beyond the diagonal
        for (int s = 0; s < smax; s++){
            float vv = b2f(vb[(size_t)s*64 + d]);
            const uint4* ar = reinterpret_cast<const uint4*>(&At[s][tq*32]);
#pragma unroll
            for (int u = 0; u < 4; u++){
                uint4 av = ar[u];
                acc[u*8+0] += b2f_lo(av.x)*vv; acc[u*8+1] += b2f_hi(av.x)*vv;
                acc[u*8+2] += b2f_lo(av.y)*vv; acc[u*8+3] += b2f_hi(av.y)*vv;
                acc[u*8+4] += b2f_lo(av.z)*vv; acc[u*8+5] += b2f_hi(av.z)*vv;
                acc[u*8+6] += b2f_lo(av.w)*vv; acc[u*8+7] += b2f_hi(av.w)*vv;
            }
        }
        for (int f = 0; f < 128; f++){
            float sv = Sb[(size_t)f*64 + d];
            const uint4* qr = reinterpret_cast<const uint4*>(&Qt[f][tq*32]);
#pragma unroll
            for (int u = 0; u < 4; u++){
                uint4 qv4 = qr[u];
                acc[u*8+0] += b2f_lo(qv4.x)*sv; acc[u*8+1] += b2f_hi(qv4.x)*sv;
                acc[u*8+2] += b2f_lo(qv4.y)*sv; acc[u*8+3] += b2f_hi(qv4.y)*sv;
                acc[u*8+4] += b2f_lo(qv4.z)*sv; acc[u*8+5] += b2f_hi(qv4.z)*sv;
                acc[u*8+6] += b2f_lo(qv4.w)*sv; acc[u*8+7] += b2f_hi(qv4.w)*sv;
            }
        }
        const volatile float* dg = (const volatile float*)(deng + (size_t)blk*128);
#pragma unroll
        for (int i = 0; i < 32; i++){
            int t = tq*32 + i;
            float den = dg[t];
            size_t row = (size_t)b*2048 + t0 + t;
            y2d[row*1024 + h*64 + d] = f2b(acc[i] / den);
        }
    }
}

extern "C" void kernel_launch(void* const* d_in, const int* in_sizes, int n_in,
                              void* d_out, int out_size, void* d_ws, size_t ws_size,
                              hipStream_t stream)
{
    (void)in_sizes; (void)n_in; (void)out_size; (void)ws_size;
    const float* x  = (const float*)d_in[0];
    const float* Wq = (const float*)d_in[1];
    const float* Wk = (const float*)d_in[2];
    const float* Wv = (const float*)d_in[3];
    const float* Wo = (const float*)d_in[4];
    const float* Wf = (const float*)d_in[5];
    float* out = (float*)d_out;   // reference output dtype is float32
    char* ws = (char*)d_ws;

    // workspace layout (lifetime-aliased, total ~137 MiB)
    float* qkf = (float*)(ws + 0);           // 32MB fp32 (B,H,T,HD): q then k (dead after featmap)
    float* Ss  = (float*)(ws + 0);           // alias qkf: (B,H,NC,NF,HD) fp32, 32MB
    u16*   vh  = (u16*)  (ws + 33554432);    // 16MB bf16 (B,H,T,HD)
    u16*   qp  = (u16*)  (ws + 50331648);    // 32MB bf16 (B,H,T,NF)
    u16*   kp  = (u16*)  (ws + 83886080);    // 32MB bf16
    u16*   y2d = (u16*)  (ws + 117440512);   // 16MB bf16 (B*T, H*HD)
    u16*   WTq = (u16*)  (ws + 134217728);   // 2MB bf16 each
    u16*   WTk = (u16*)  (ws + 136314880);
    u16*   WTv = (u16*)  (ws + 138412032);
    u16*   WTo = (u16*)  (ws + 140509184);
    float* zs  = (float*)(ws + 142606336);   // (B,H,NC,NF) fp32, 0.5MB
    float* deng= (float*)(ws + 143130624);   // (B*H*NC,128) fp32, 0.5MB

    dim3 tgrid(16, 16);
    transpose1024<<<tgrid, 256, 0, stream>>>(Wq, WTq);
    transpose1024<<<tgrid, 256, 0, stream>>>(Wk, WTk);
    transpose1024<<<tgrid, 256, 0, stream>>>(Wv, WTv);
    transpose1024<<<tgrid, 256, 0, stream>>>(Wo, WTo);

    dim3 ggrid(64, 8);
    // q -> qkf (fp32, remapped), featurize, then reuse qkf for k
    gemm128<0,1><<<ggrid, 256, 0, stream>>>(x, WTq, qkf, nullptr);
    featmap<<<65536, 256, 0, stream>>>(qkf, Wf, qp);
    gemm128<0,1><<<ggrid, 256, 0, stream>>>(x, WTk, qkf, nullptr);
    featmap<<<65536, 256, 0, stream>>>(qkf, Wf, kp);
    gemm128<1,1><<<ggrid, 256, 0, stream>>>(x, WTv, nullptr, vh);

    chunk_sum<<<1024, 256, 0, stream>>>(kp, vh, Ss, zs);
    prefix_chunks<<<64, 256, 0, stream>>>(Ss, zs);
    chunk_out<<<1024, 256, 0, stream>>>(qp, kp, vh, Ss, zs, deng, y2d);

    gemm128<2,0><<<ggrid, 256, 0, stream>>>(y2d, WTo, out, nullptr);
}

// Round 5
// 623.910 us; speedup vs baseline: 1.6153x; 1.6153x over previous
//
#include <hip/hip_runtime.h>
#include <hip/hip_bf16.h>

typedef unsigned int u32;
typedef unsigned short u16;
typedef __bf16 bf16x8 __attribute__((ext_vector_type(8)));
typedef float f32x4 __attribute__((ext_vector_type(4)));

// ---------- bf16 bit helpers ----------
__device__ __forceinline__ float b2f(u16 s){ union{u32 x; float f;} c; c.x = ((u32)s) << 16; return c.f; }
__device__ __forceinline__ float b2f_lo(u32 u){ union{u32 x; float f;} c; c.x = u << 16; return c.f; }
__device__ __forceinline__ float b2f_hi(u32 u){ union{u32 x; float f;} c; c.x = u & 0xFFFF0000u; return c.f; }
__device__ __forceinline__ u16 f2b(float f){
    union{float f; u32 u;} c; c.f = f;
    u32 r = c.u + 0x7FFFu + ((c.u >> 16) & 1u);
    return (u16)(r >> 16);
}
__device__ __forceinline__ u32 pk(float lo, float hi){
    return (u32)f2b(lo) | ((u32)f2b(hi) << 16);
}

// Problem constants: B=4, T=2048, D=1024, H=16, HD=64, NF=128, chunk C=128, NC=16
// All inputs FLOAT32; OUTPUT is FLOAT32.

// ---------- 1024x1024 transpose + fp32->bf16 convert (weights -> W^T bf16) ----------
__global__ __launch_bounds__(256) void transpose1024(const float* __restrict__ in, u16* __restrict__ out)
{
    __shared__ u16 tile[64][72];
    int kb = blockIdx.x * 64, nb = blockIdx.y * 64, tid = threadIdx.x;
#pragma unroll
    for (int i = 0; i < 2; i++){
        int idx = tid + 256*i; int r = idx >> 3; int c8 = (idx & 7) * 8;
        const float* p = &in[(size_t)(kb + r)*1024 + nb + c8];
        float4 lo = *reinterpret_cast<const float4*>(p);
        float4 hi = *reinterpret_cast<const float4*>(p + 4);
        uint4 v;
        v.x = pk(lo.x, lo.y); v.y = pk(lo.z, lo.w);
        v.z = pk(hi.x, hi.y); v.w = pk(hi.z, hi.w);
        *reinterpret_cast<uint4*>(&tile[r][c8]) = v;
    }
    __syncthreads();
#pragma unroll
    for (int i = 0; i < 2; i++){
        int idx = tid + 256*i; int c = idx >> 3; int r8 = (idx & 7) * 8;
        u32 w[4];
#pragma unroll
        for (int j = 0; j < 4; j++)
            w[j] = (u32)tile[r8 + 2*j][c] | ((u32)tile[r8 + 2*j + 1][c] << 16);
        uint4 v; v.x = w[0]; v.y = w[1]; v.z = w[2]; v.w = w[3];
        *reinterpret_cast<uint4*>(&out[(size_t)(nb + c)*1024 + kb + r8]) = v;
    }
}

// ---------- MFMA bf16 GEMM: C[8192,1024] = A[8192,1024] * W[1024,1024], BT = bf16 W^T ----------
// AF32: A is fp32 (converted to bf16 during staging); else A is bf16.
// MODE 0: write fp32, remapped (B,H,T,HD)
// MODE 1: write bf16, remapped (B,H,T,HD)
// MODE 2: write fp32, plain row-major (final output)
template<int MODE, int AF32>
__global__ __launch_bounds__(256) void gemm128(const void* __restrict__ Ap, const u16* __restrict__ BT,
                                               float* __restrict__ outf, u16* __restrict__ outh)
{
    __shared__ u16 As[128][40];   // [m][k], 80B rows (16B aligned, <=2-way banks = free)
    __shared__ u16 Bs[128][40];   // [n][k] (rows of W^T)
    int tid = threadIdx.x; int lane = tid & 63; int w = tid >> 6;
    int m0 = blockIdx.x * 128, n0 = blockIdx.y * 128;
    int wm = (w >> 1) * 64, wn = (w & 1) * 64;
    int fr = lane & 15, fk = (lane >> 4) * 8;
    f32x4 acc[4][4] = {};
    int lr = tid >> 2;          // 0..63
    int lk = (tid & 3) * 8;     // 0,8,16,24
    const u16*   A16 = (const u16*)Ap;
    const float* A32 = (const float*)Ap;
    for (int k0 = 0; k0 < 1024; k0 += 32){
        uint4 a0, a1, b0, b1;
        if (AF32){
            const float* p0 = &A32[(size_t)(m0 + lr)*1024 + k0 + lk];
            const float* p1 = &A32[(size_t)(m0 + 64 + lr)*1024 + k0 + lk];
            float4 l0 = *reinterpret_cast<const float4*>(p0);
            float4 h0 = *reinterpret_cast<const float4*>(p0 + 4);
            float4 l1 = *reinterpret_cast<const float4*>(p1);
            float4 h1 = *reinterpret_cast<const float4*>(p1 + 4);
            a0.x = pk(l0.x, l0.y); a0.y = pk(l0.z, l0.w); a0.z = pk(h0.x, h0.y); a0.w = pk(h0.z, h0.w);
            a1.x = pk(l1.x, l1.y); a1.y = pk(l1.z, l1.w); a1.z = pk(h1.x, h1.y); a1.w = pk(h1.z, h1.w);
        } else {
            a0 = *reinterpret_cast<const uint4*>(&A16[(size_t)(m0 + lr)*1024 + k0 + lk]);
            a1 = *reinterpret_cast<const uint4*>(&A16[(size_t)(m0 + 64 + lr)*1024 + k0 + lk]);
        }
        b0 = *reinterpret_cast<const uint4*>(&BT[(size_t)(n0 + lr)*1024 + k0 + lk]);
        b1 = *reinterpret_cast<const uint4*>(&BT[(size_t)(n0 + 64 + lr)*1024 + k0 + lk]);
        __syncthreads();
        *reinterpret_cast<uint4*>(&As[lr][lk])      = a0;
        *reinterpret_cast<uint4*>(&As[64 + lr][lk]) = a1;
        *reinterpret_cast<uint4*>(&Bs[lr][lk])      = b0;
        *reinterpret_cast<uint4*>(&Bs[64 + lr][lk]) = b1;
        __syncthreads();
        bf16x8 af[4], bf[4];
#pragma unroll
        for (int i = 0; i < 4; i++){
            af[i] = *reinterpret_cast<const bf16x8*>(&As[wm + i*16 + fr][fk]);
            bf[i] = *reinterpret_cast<const bf16x8*>(&Bs[wn + i*16 + fr][fk]);
        }
#pragma unroll
        for (int i = 0; i < 4; i++)
#pragma unroll
            for (int j = 0; j < 4; j++)
                acc[i][j] = __builtin_amdgcn_mfma_f32_16x16x32_bf16(af[i], bf[j], acc[i][j], 0, 0, 0);
    }
#pragma unroll
    for (int i = 0; i < 4; i++){
        int row0 = m0 + wm + i*16 + ((lane >> 4) << 2);
#pragma unroll
        for (int j = 0; j < 4; j++){
            int col = n0 + wn + j*16 + fr;
#pragma unroll
            for (int r = 0; r < 4; r++){
                float val = acc[i][j][r];
                int row = row0 + r;
                if (MODE == 2){
                    outf[(size_t)row*1024 + col] = val;
                } else {
                    int bb = row >> 11, t = row & 2047, h = col >> 6, d = col & 63;
                    size_t idx = (((size_t)(bb*16 + h))*2048 + t)*64 + d;
                    if (MODE == 0) outf[idx] = val;
                    else           outh[idx] = f2b(val);
                }
            }
        }
    }
}

// ---------- FAVOR+ feature map: phi = exp(x.Wf - 0.5||x||^2)/sqrt(NF) ----------
__global__ __launch_bounds__(256) void featmap(const float* __restrict__ xf, const float* __restrict__ Wf,
                                               u16* __restrict__ xp)
{
    __shared__ float xs[2][64];
    int tid = threadIdx.x;
    int half = tid >> 7, f = tid & 127;
    size_t tok = (size_t)blockIdx.x * 2 + half;
    if (f < 64) xs[half][f] = xf[tok*64 + f];
    __syncthreads();
    float dq = 0.f, sq = 0.f;
#pragma unroll
    for (int d = 0; d < 64; d++){
        float wv = Wf[d*128 + f];
        float qd = xs[half][d];
        dq += qd*wv; sq += qd*qd;
    }
    const float c = 0.08838834764831845f; // 1/sqrt(128)
    xp[tok*128 + f] = f2b(__expf(fminf(dq - 0.5f*sq, 60.f)) * c);
}

// ---------- per-chunk KV summaries: S_c^T[d][f] (bf16), z_c = colsum(Kp_c) ----------
__global__ __launch_bounds__(256) void chunk_sum(const u16* __restrict__ kp, const u16* __restrict__ vh,
                                                 u16* __restrict__ Sa, float* __restrict__ zs)
{
    __shared__ u16 Kl[128][128];
    __shared__ u16 Vl[128][64];
    int blk = blockIdx.x, tid = threadIdx.x;
    int bh = blk >> 4, c = blk & 15;
    const u16* kpb = kp + ((size_t)bh*2048 + c*128)*128;
    const u16* vb  = vh + ((size_t)bh*2048 + c*128)*64;
#pragma unroll
    for (int i = 0; i < 8; i++){ int idx = tid + 256*i; int t = idx >> 4, f8 = (idx & 15)*8;
        *reinterpret_cast<uint4*>(&Kl[t][f8]) = *reinterpret_cast<const uint4*>(&kpb[(size_t)t*128 + f8]); }
#pragma unroll
    for (int i = 0; i < 4; i++){ int idx = tid + 256*i; int t = idx >> 3, d8 = (idx & 7)*8;
        *reinterpret_cast<uint4*>(&Vl[t][d8]) = *reinterpret_cast<const uint4*>(&vb[(size_t)t*64 + d8]); }
    __syncthreads();
    int d = tid & 63, fq = tid >> 6;
    float acc[32];
#pragma unroll
    for (int i = 0; i < 32; i++) acc[i] = 0.f;
    for (int t = 0; t < 128; t++){
        float vd = b2f(Vl[t][d]);
        const u32* kr = reinterpret_cast<const u32*>(&Kl[t][fq*32]);
#pragma unroll
        for (int i = 0; i < 16; i++){
            u32 u = kr[i];
            acc[2*i]     += b2f_lo(u) * vd;
            acc[2*i + 1] += b2f_hi(u) * vd;
        }
    }
    // write S^T[d][f] as bf16, vectorized (each thread owns f=fq*32..+31 at fixed d)
    u16* Sb = Sa + (size_t)blk*8192 + (size_t)d*128 + fq*32;
#pragma unroll
    for (int v4 = 0; v4 < 4; v4++){
        uint4 o;
        o.x = pk(acc[v4*8+0], acc[v4*8+1]);
        o.y = pk(acc[v4*8+2], acc[v4*8+3]);
        o.z = pk(acc[v4*8+4], acc[v4*8+5]);
        o.w = pk(acc[v4*8+6], acc[v4*8+7]);
        *reinterpret_cast<uint4*>(Sb + v4*8) = o;
    }
    if (tid < 128){
        float z = 0.f;
        for (int t = 0; t < 128; t++) z += b2f(Kl[t][tid]);
        zs[(size_t)blk*128 + tid] = z;
    }
}

// ---------- exclusive prefix over the 16 chunks (per bh), bf16 in/out ----------
__global__ __launch_bounds__(256) void prefix_chunks(const u16* __restrict__ Sa, u16* __restrict__ Sb,
                                                     float* __restrict__ zs)
{
    int bh = blockIdx.x, seg = blockIdx.y, tid = threadIdx.x;
    const u16* src = Sa + (size_t)bh*16*8192;
    u16*       dst = Sb + (size_t)bh*16*8192;
#pragma unroll
    for (int it = 0; it < 4; it++){
        int e = seg*1024 + it*256 + tid;
        float run = 0.f;
#pragma unroll
        for (int c = 0; c < 16; c++){
            float v = b2f(src[(size_t)c*8192 + e]);
            dst[(size_t)c*8192 + e] = f2b(run);
            run += v;
        }
    }
    if (seg == 0 && tid < 128){
        float run = 0.f; float* zp = zs + (size_t)bh*16*128 + tid;
#pragma unroll
        for (int c = 0; c < 16; c++){ float v = zp[c*128]; zp[c*128] = run; run += v; }
    }
}

// ---------- per-chunk output via MFMA ----------
// P = tril(Qp Kp^T) (bf16, LDS round-trip); O = P V + Qp S_in; den = rowsum(P) + Qp.z_in + eps
__global__ __launch_bounds__(256) void chunk_out(const u16* __restrict__ qp, const u16* __restrict__ kp,
                                                 const u16* __restrict__ vh, const u16* __restrict__ St,
                                                 const float* __restrict__ zs, u16* __restrict__ y2d)
{
    __shared__ u16 P[128][136];    // scores [t][s], masked, 272B rows (16B aligned, 2-way banks)
    __shared__ u16 Vt[64][136];    // V transposed [d][t]
    __shared__ float denl[128];
    int blk = blockIdx.x, tid = threadIdx.x;
    int lane = tid & 63, w = tid >> 6;
    int m = lane & 15, q = lane >> 4;
    int bh = blk >> 4, c = blk & 15;
    int b = bh >> 4, h = bh & 15, t0 = c*128;
    const u16* qpb = qp + ((size_t)bh*2048 + t0)*128;
    const u16* kpb = kp + ((size_t)bh*2048 + t0)*128;
    const u16* vb  = vh + ((size_t)bh*2048 + t0)*64;
    const u16* Stb = St + (size_t)blk*8192;   // [d][f] bf16
    const float* zb = zs + (size_t)blk*128;

    // stage V transposed: Vt[d][t]
#pragma unroll
    for (int it = 0; it < 4; it++){
        int idx = tid + 256*it;
        int t = idx >> 3, d8 = (idx & 7)*8;
        uint4 v = *reinterpret_cast<const uint4*>(&vb[(size_t)t*64 + d8]);
        u32 ww[4] = {v.x, v.y, v.z, v.w};
#pragma unroll
        for (int j = 0; j < 4; j++){
            Vt[d8 + 2*j][t]     = (u16)(ww[j] & 0xFFFFu);
            Vt[d8 + 2*j + 1][t] = (u16)(ww[j] >> 16);
        }
    }
    // zero strict-upper tiles of P: row t, s in [16*(t/16+1), 128)
    {
        int row = tid >> 1, half = tid & 1;
        int i = row >> 4;
        for (int s2 = 16*(i + 1) + half*2; s2 < 128; s2 += 4)
            *reinterpret_cast<u32*>(&P[row][s2]) = 0;
    }
    // phase A: QK^T over 36 lower-triangle 16x16 tiles, round-robin across 4 waves
    {
        static const unsigned char TIa[36] = {0,1,1,2,2,2,3,3,3,3,4,4,4,4,4,
                                              5,5,5,5,5,5,6,6,6,6,6,6,6,7,7,7,7,7,7,7,7};
        static const unsigned char TJa[36] = {0,0,1,0,1,2,0,1,2,3,0,1,2,3,4,
                                              0,1,2,3,4,5,0,1,2,3,4,5,6,0,1,2,3,4,5,6,7};
        for (int idx = w; idx < 36; idx += 4){
            int i = TIa[idx], j = TJa[idx];
            f32x4 a = {};
            const u16* arow = qpb + (size_t)(i*16 + m)*128 + q*8;
            const u16* brow = kpb + (size_t)(j*16 + m)*128 + q*8;
#pragma unroll
            for (int ks = 0; ks < 4; ks++){
                bf16x8 af = *reinterpret_cast<const bf16x8*>(arow + ks*32);
                bf16x8 bf = *reinterpret_cast<const bf16x8*>(brow + ks*32);
                a = __builtin_amdgcn_mfma_f32_16x16x32_bf16(af, bf, a, 0, 0, 0);
            }
            int scol = j*16 + m;
#pragma unroll
            for (int r = 0; r < 4; r++){
                int trow = i*16 + q*4 + r;
                P[trow][scol] = (scol <= trow) ? f2b(a[r]) : (u16)0;
            }
        }
    }
    __syncthreads();
    // denominator (threads 0..127): rowsum(P) + Qp.z + eps
    if (tid < 128){
        int t = tid;
        float dd = 1e-6f;
        const u32* pr = reinterpret_cast<const u32*>(&P[t][0]);
#pragma unroll
        for (int s2 = 0; s2 < 64; s2++){ u32 u = pr[s2]; dd += b2f_lo(u) + b2f_hi(u); }
        const u16* qrow = qpb + (size_t)t*128;
        for (int f = 0; f < 128; f++) dd += b2f(qrow[f]) * zb[f];
        denl[t] = dd;
    }
    // phase B: O[t][d] = P.V + Qp.S_in ; wave w owns rows [32w, 32w+32), all 64 d
    f32x4 acc[2][4] = {};
    // PV: causal-zero above s=32w+31 -> only k-steps 0..w
    for (int ks = 0; ks <= w; ks++){
        bf16x8 af[2], bf4[4];
#pragma unroll
        for (int mt = 0; mt < 2; mt++)
            af[mt] = *reinterpret_cast<const bf16x8*>(&P[32*w + mt*16 + m][ks*32 + q*8]);
#pragma unroll
        for (int nt = 0; nt < 4; nt++)
            bf4[nt] = *reinterpret_cast<const bf16x8*>(&Vt[nt*16 + m][ks*32 + q*8]);
#pragma unroll
        for (int mt = 0; mt < 2; mt++)
#pragma unroll
            for (int nt = 0; nt < 4; nt++)
                acc[mt][nt] = __builtin_amdgcn_mfma_f32_16x16x32_bf16(af[mt], bf4[nt], acc[mt][nt], 0, 0, 0);
    }
    // Qp . S_in: A-frags from global qp rows, B-frags from global S^T rows
#pragma unroll
    for (int ks = 0; ks < 4; ks++){
        bf16x8 af[2], bf4[4];
#pragma unroll
        for (int mt = 0; mt < 2; mt++)
            af[mt] = *reinterpret_cast<const bf16x8*>(qpb + (size_t)(32*w + mt*16 + m)*128 + ks*32 + q*8);
#pragma unroll
        for (int nt = 0; nt < 4; nt++)
            bf4[nt] = *reinterpret_cast<const bf16x8*>(Stb + (size_t)(nt*16 + m)*128 + ks*32 + q*8);
#pragma unroll
        for (int mt = 0; mt < 2; mt++)
#pragma unroll
            for (int nt = 0; nt < 4; nt++)
                acc[mt][nt] = __builtin_amdgcn_mfma_f32_16x16x32_bf16(af[mt], bf4[nt], acc[mt][nt], 0, 0, 0);
    }
    __syncthreads();   // denl visible
    // epilogue
#pragma unroll
    for (int mt = 0; mt < 2; mt++){
#pragma unroll
        for (int nt = 0; nt < 4; nt++){
#pragma unroll
            for (int r = 0; r < 4; r++){
                int t = 32*w + mt*16 + q*4 + r;
                int d = nt*16 + m;
                y2d[((size_t)b*2048 + t0 + t)*1024 + h*64 + d] = f2b(acc[mt][nt][r] / denl[t]);
            }
        }
    }
}

extern "C" void kernel_launch(void* const* d_in, const int* in_sizes, int n_in,
                              void* d_out, int out_size, void* d_ws, size_t ws_size,
                              hipStream_t stream)
{
    (void)in_sizes; (void)n_in; (void)out_size; (void)ws_size;
    const float* x  = (const float*)d_in[0];
    const float* Wq = (const float*)d_in[1];
    const float* Wk = (const float*)d_in[2];
    const float* Wv = (const float*)d_in[3];
    const float* Wo = (const float*)d_in[4];
    const float* Wf = (const float*)d_in[5];
    float* out = (float*)d_out;
    char* ws = (char*)d_ws;

    // workspace layout (lifetime-aliased, total ~137 MiB)
    float* qkf = (float*)(ws + 0);           // 32MB fp32 (B,H,T,HD): q then k (dead after featmap)
    u16*   Sa  = (u16*)  (ws + 0);           // alias: chunk S^T raw bf16 [1024][64][128], 16MB
    u16*   Sbp = (u16*)  (ws + 16777216);    // alias: exclusive-prefix S^T bf16, 16MB
    u16*   vh  = (u16*)  (ws + 33554432);    // 16MB bf16 (B,H,T,HD)
    u16*   qp  = (u16*)  (ws + 50331648);    // 32MB bf16 (B,H,T,NF)
    u16*   kp  = (u16*)  (ws + 83886080);    // 32MB bf16
    u16*   y2d = (u16*)  (ws + 117440512);   // 16MB bf16 (B*T, H*HD)
    u16*   WTq = (u16*)  (ws + 134217728);   // 2MB bf16 each
    u16*   WTk = (u16*)  (ws + 136314880);
    u16*   WTv = (u16*)  (ws + 138412032);
    u16*   WTo = (u16*)  (ws + 140509184);
    float* zs  = (float*)(ws + 142606336);   // (B,H,NC,NF) fp32, 0.5MB

    dim3 tgrid(16, 16);
    transpose1024<<<tgrid, 256, 0, stream>>>(Wq, WTq);
    transpose1024<<<tgrid, 256, 0, stream>>>(Wk, WTk);
    transpose1024<<<tgrid, 256, 0, stream>>>(Wv, WTv);
    transpose1024<<<tgrid, 256, 0, stream>>>(Wo, WTo);

    dim3 ggrid(64, 8);
    // q -> qkf (fp32, remapped), featurize, then reuse qkf for k
    gemm128<0,1><<<ggrid, 256, 0, stream>>>(x, WTq, qkf, nullptr);
    featmap<<<65536, 256, 0, stream>>>(qkf, Wf, qp);
    gemm128<0,1><<<ggrid, 256, 0, stream>>>(x, WTk, qkf, nullptr);
    featmap<<<65536, 256, 0, stream>>>(qkf, Wf, kp);
    gemm128<1,1><<<ggrid, 256, 0, stream>>>(x, WTv, nullptr, vh);

    chunk_sum<<<1024, 256, 0, stream>>>(kp, vh, Sa, zs);
    prefix_chunks<<<dim3(64, 8), 256, 0, stream>>>(Sa, Sbp, zs);
    chunk_out<<<1024, 256, 0, stream>>>(qp, kp, vh, Sbp, zs, y2d);

    gemm128<2,0><<<ggrid, 256, 0, stream>>>(y2d, WTo, out, nullptr);
}

// Round 6
// 402.629 us; speedup vs baseline: 2.5030x; 1.5496x over previous
//
#include <hip/hip_runtime.h>
#include <hip/hip_bf16.h>

typedef unsigned int u32;
typedef unsigned short u16;
typedef __bf16 bf16x8 __attribute__((ext_vector_type(8)));
typedef float f32x4 __attribute__((ext_vector_type(4)));

// ---------- bf16 bit helpers ----------
__device__ __forceinline__ float b2f(u16 s){ union{u32 x; float f;} c; c.x = ((u32)s) << 16; return c.f; }
__device__ __forceinline__ float b2f_lo(u32 u){ union{u32 x; float f;} c; c.x = u << 16; return c.f; }
__device__ __forceinline__ float b2f_hi(u32 u){ union{u32 x; float f;} c; c.x = u & 0xFFFF0000u; return c.f; }
__device__ __forceinline__ u16 f2b(float f){
    union{float f; u32 u;} c; c.f = f;
    u32 r = c.u + 0x7FFFu + ((c.u >> 16) & 1u);
    return (u16)(r >> 16);
}
__device__ __forceinline__ u32 pk(float lo, float hi){
    return (u32)f2b(lo) | ((u32)f2b(hi) << 16);
}

// Problem constants: B=4, T=2048, D=1024, H=16, HD=64, NF=128, chunk C=128, NC=16
// All inputs FLOAT32; OUTPUT is FLOAT32.

// ---------- 1024x1024 transpose + fp32->bf16 convert (weights -> W^T bf16) ----------
__global__ __launch_bounds__(256) void transpose1024(const float* __restrict__ in, u16* __restrict__ out)
{
    __shared__ u16 tile[64][72];
    int kb = blockIdx.x * 64, nb = blockIdx.y * 64, tid = threadIdx.x;
#pragma unroll
    for (int i = 0; i < 2; i++){
        int idx = tid + 256*i; int r = idx >> 3; int c8 = (idx & 7) * 8;
        const float* p = &in[(size_t)(kb + r)*1024 + nb + c8];
        float4 lo = *reinterpret_cast<const float4*>(p);
        float4 hi = *reinterpret_cast<const float4*>(p + 4);
        uint4 v;
        v.x = pk(lo.x, lo.y); v.y = pk(lo.z, lo.w);
        v.z = pk(hi.x, hi.y); v.w = pk(hi.z, hi.w);
        *reinterpret_cast<uint4*>(&tile[r][c8]) = v;
    }
    __syncthreads();
#pragma unroll
    for (int i = 0; i < 2; i++){
        int idx = tid + 256*i; int c = idx >> 3; int r8 = (idx & 7) * 8;
        u32 w[4];
#pragma unroll
        for (int j = 0; j < 4; j++)
            w[j] = (u32)tile[r8 + 2*j][c] | ((u32)tile[r8 + 2*j + 1][c] << 16);
        uint4 v; v.x = w[0]; v.y = w[1]; v.z = w[2]; v.w = w[3];
        *reinterpret_cast<uint4*>(&out[(size_t)(nb + c)*1024 + kb + r8]) = v;
    }
}

// ---------- MFMA bf16 GEMM: C[8192,1024] = A[8192,1024] * W[1024,1024], BT = bf16 W^T ----------
// AF32: A is fp32 (converted to bf16 during staging); else A is bf16.
// MODE 1: write bf16, remapped (B,H,T,HD)
// MODE 2: write fp32, plain row-major (final output)
template<int MODE, int AF32>
__global__ __launch_bounds__(256) void gemm128(const void* __restrict__ Ap, const u16* __restrict__ BT,
                                               float* __restrict__ outf, u16* __restrict__ outh)
{
    __shared__ u16 As[128][40];   // [m][k], 80B rows (16B aligned, <=2-way banks = free)
    __shared__ u16 Bs[128][40];   // [n][k] (rows of W^T)
    int tid = threadIdx.x; int lane = tid & 63; int w = tid >> 6;
    int m0 = blockIdx.x * 128, n0 = blockIdx.y * 128;
    int wm = (w >> 1) * 64, wn = (w & 1) * 64;
    int fr = lane & 15, fk = (lane >> 4) * 8;
    f32x4 acc[4][4] = {};
    int lr = tid >> 2;          // 0..63
    int lk = (tid & 3) * 8;     // 0,8,16,24
    const u16*   A16 = (const u16*)Ap;
    const float* A32 = (const float*)Ap;
    for (int k0 = 0; k0 < 1024; k0 += 32){
        uint4 a0, a1, b0, b1;
        if (AF32){
            const float* p0 = &A32[(size_t)(m0 + lr)*1024 + k0 + lk];
            const float* p1 = &A32[(size_t)(m0 + 64 + lr)*1024 + k0 + lk];
            float4 l0 = *reinterpret_cast<const float4*>(p0);
            float4 h0 = *reinterpret_cast<const float4*>(p0 + 4);
            float4 l1 = *reinterpret_cast<const float4*>(p1);
            float4 h1 = *reinterpret_cast<const float4*>(p1 + 4);
            a0.x = pk(l0.x, l0.y); a0.y = pk(l0.z, l0.w); a0.z = pk(h0.x, h0.y); a0.w = pk(h0.z, h0.w);
            a1.x = pk(l1.x, l1.y); a1.y = pk(l1.z, l1.w); a1.z = pk(h1.x, h1.y); a1.w = pk(h1.z, h1.w);
        } else {
            a0 = *reinterpret_cast<const uint4*>(&A16[(size_t)(m0 + lr)*1024 + k0 + lk]);
            a1 = *reinterpret_cast<const uint4*>(&A16[(size_t)(m0 + 64 + lr)*1024 + k0 + lk]);
        }
        b0 = *reinterpret_cast<const uint4*>(&BT[(size_t)(n0 + lr)*1024 + k0 + lk]);
        b1 = *reinterpret_cast<const uint4*>(&BT[(size_t)(n0 + 64 + lr)*1024 + k0 + lk]);
        __syncthreads();
        *reinterpret_cast<uint4*>(&As[lr][lk])      = a0;
        *reinterpret_cast<uint4*>(&As[64 + lr][lk]) = a1;
        *reinterpret_cast<uint4*>(&Bs[lr][lk])      = b0;
        *reinterpret_cast<uint4*>(&Bs[64 + lr][lk]) = b1;
        __syncthreads();
        bf16x8 af[4], bf[4];
#pragma unroll
        for (int i = 0; i < 4; i++){
            af[i] = *reinterpret_cast<const bf16x8*>(&As[wm + i*16 + fr][fk]);
            bf[i] = *reinterpret_cast<const bf16x8*>(&Bs[wn + i*16 + fr][fk]);
        }
#pragma unroll
        for (int i = 0; i < 4; i++)
#pragma unroll
            for (int j = 0; j < 4; j++)
                acc[i][j] = __builtin_amdgcn_mfma_f32_16x16x32_bf16(af[i], bf[j], acc[i][j], 0, 0, 0);
    }
#pragma unroll
    for (int i = 0; i < 4; i++){
        int row0 = m0 + wm + i*16 + ((lane >> 4) << 2);
#pragma unroll
        for (int j = 0; j < 4; j++){
            int col = n0 + wn + j*16 + fr;
#pragma unroll
            for (int r = 0; r < 4; r++){
                float val = acc[i][j][r];
                int row = row0 + r;
                if (MODE == 2){
                    outf[(size_t)row*1024 + col] = val;
                } else {
                    int bb = row >> 11, t = row & 2047, h = col >> 6, d = col & 63;
                    size_t idx = (((size_t)(bb*16 + h))*2048 + t)*64 + d;
                    outh[idx] = f2b(val);
                }
            }
        }
    }
}

// ---------- FAVOR+ feature map via MFMA: phi = exp(x.Wf - 0.5||x||^2)/sqrt(NF) ----------
// xh: (tokens,64) bf16; Wf: (64,128) fp32; xp: (tokens,128) bf16. 128 tokens/block.
__global__ __launch_bounds__(256) void featmap_mfma(const u16* __restrict__ xh, const float* __restrict__ Wf,
                                                    u16* __restrict__ xp)
{
    __shared__ u16 Xl[128][72];    // token x d, 144B rows (16B aligned)
    __shared__ u16 Wft[128][72];   // f x d (W_feat transposed)
    __shared__ float sqp[128][8];
    __shared__ float sql[128];
    int tid = threadIdx.x;
    int lane = tid & 63, w = tid >> 6;
    int m = lane & 15, q = lane >> 4;
    const u16* xb = xh + (size_t)blockIdx.x * 128 * 64;
    // stage X + sq partials (fp32 accumulation of bf16 values)
#pragma unroll
    for (int it = 0; it < 4; it++){
        int idx = tid + 256*it;
        int row = idx >> 3, c8 = (idx & 7) * 8;
        uint4 v = *reinterpret_cast<const uint4*>(xb + (size_t)row*64 + c8);
        *reinterpret_cast<uint4*>(&Xl[row][c8]) = v;
        u32 ww[4] = {v.x, v.y, v.z, v.w};
        float s = 0.f;
#pragma unroll
        for (int j = 0; j < 4; j++){
            float a = b2f_lo(ww[j]), bb = b2f_hi(ww[j]);
            s += a*a + bb*bb;
        }
        sqp[row][idx & 7] = s;
    }
    // stage Wf^T bf16
#pragma unroll
    for (int it = 0; it < 8; it++){
        int idx = tid + 256*it;
        int d = idx >> 5, f4 = (idx & 31) * 4;
        float4 v = *reinterpret_cast<const float4*>(Wf + d*128 + f4);
        Wft[f4+0][d] = f2b(v.x); Wft[f4+1][d] = f2b(v.y);
        Wft[f4+2][d] = f2b(v.z); Wft[f4+3][d] = f2b(v.w);
    }
    __syncthreads();
    if (tid < 128){
        float s = 0.f;
#pragma unroll
        for (int j = 0; j < 8; j++) s += sqp[tid][j];
        sql[tid] = s;
    }
    // MFMA: wave w -> tokens [32w,32w+32), features 0..127
    f32x4 acc[2][8] = {};
#pragma unroll
    for (int ks = 0; ks < 2; ks++){
        bf16x8 af[2], bf[8];
#pragma unroll
        for (int mt = 0; mt < 2; mt++)
            af[mt] = *reinterpret_cast<const bf16x8*>(&Xl[32*w + mt*16 + m][ks*32 + q*8]);
#pragma unroll
        for (int nt = 0; nt < 8; nt++)
            bf[nt] = *reinterpret_cast<const bf16x8*>(&Wft[nt*16 + m][ks*32 + q*8]);
#pragma unroll
        for (int mt = 0; mt < 2; mt++)
#pragma unroll
            for (int nt = 0; nt < 8; nt++)
                acc[mt][nt] = __builtin_amdgcn_mfma_f32_16x16x32_bf16(af[mt], bf[nt], acc[mt][nt], 0, 0, 0);
    }
    __syncthreads();   // sql visible to all lanes
    const float c = 0.08838834764831845f; // 1/sqrt(128)
    u16* xpb = xp + (size_t)blockIdx.x * 128 * 128;
#pragma unroll
    for (int mt = 0; mt < 2; mt++){
#pragma unroll
        for (int r = 0; r < 4; r++){
            int t = 32*w + mt*16 + q*4 + r;
            float hs = 0.5f * sql[t];
#pragma unroll
            for (int nt = 0; nt < 8; nt++){
                int f = nt*16 + m;
                xpb[(size_t)t*128 + f] = f2b(__expf(fminf(acc[mt][nt][r] - hs, 60.f)) * c);
            }
        }
    }
}

// ---------- per-chunk KV summaries: S_c^T[d][f] (bf16), z_c = colsum(Kp_c) ----------
__global__ __launch_bounds__(256) void chunk_sum(const u16* __restrict__ kp, const u16* __restrict__ vh,
                                                 u16* __restrict__ Sa, float* __restrict__ zs)
{
    __shared__ u16 Kl[128][128];
    __shared__ u16 Vl[128][64];
    int blk = blockIdx.x, tid = threadIdx.x;
    int bh = blk >> 4, c = blk & 15;
    const u16* kpb = kp + ((size_t)bh*2048 + c*128)*128;
    const u16* vb  = vh + ((size_t)bh*2048 + c*128)*64;
#pragma unroll
    for (int i = 0; i < 8; i++){ int idx = tid + 256*i; int t = idx >> 4, f8 = (idx & 15)*8;
        *reinterpret_cast<uint4*>(&Kl[t][f8]) = *reinterpret_cast<const uint4*>(&kpb[(size_t)t*128 + f8]); }
#pragma unroll
    for (int i = 0; i < 4; i++){ int idx = tid + 256*i; int t = idx >> 3, d8 = (idx & 7)*8;
        *reinterpret_cast<uint4*>(&Vl[t][d8]) = *reinterpret_cast<const uint4*>(&vb[(size_t)t*64 + d8]); }
    __syncthreads();
    int d = tid & 63, fq = tid >> 6;
    float acc[32];
#pragma unroll
    for (int i = 0; i < 32; i++) acc[i] = 0.f;
    for (int t = 0; t < 128; t++){
        float vd = b2f(Vl[t][d]);
        const u32* kr = reinterpret_cast<const u32*>(&Kl[t][fq*32]);
#pragma unroll
        for (int i = 0; i < 16; i++){
            u32 u = kr[i];
            acc[2*i]     += b2f_lo(u) * vd;
            acc[2*i + 1] += b2f_hi(u) * vd;
        }
    }
    u16* Sb = Sa + (size_t)blk*8192 + (size_t)d*128 + fq*32;
#pragma unroll
    for (int v4 = 0; v4 < 4; v4++){
        uint4 o;
        o.x = pk(acc[v4*8+0], acc[v4*8+1]);
        o.y = pk(acc[v4*8+2], acc[v4*8+3]);
        o.z = pk(acc[v4*8+4], acc[v4*8+5]);
        o.w = pk(acc[v4*8+6], acc[v4*8+7]);
        *reinterpret_cast<uint4*>(Sb + v4*8) = o;
    }
    if (tid < 128){
        float z = 0.f;
        for (int t = 0; t < 128; t++) z += b2f(Kl[t][tid]);
        zs[(size_t)blk*128 + tid] = z;
    }
}

// ---------- exclusive prefix over the 16 chunks (per bh), bf16 in/out ----------
__global__ __launch_bounds__(256) void prefix_chunks(const u16* __restrict__ Sa, u16* __restrict__ Sb,
                                                     float* __restrict__ zs)
{
    int bh = blockIdx.x, seg = blockIdx.y, tid = threadIdx.x;
    const u16* src = Sa + (size_t)bh*16*8192;
    u16*       dst = Sb + (size_t)bh*16*8192;
#pragma unroll
    for (int it = 0; it < 4; it++){
        int e = seg*1024 + it*256 + tid;
        float run = 0.f;
#pragma unroll
        for (int c = 0; c < 16; c++){
            float v = b2f(src[(size_t)c*8192 + e]);
            dst[(size_t)c*8192 + e] = f2b(run);
            run += v;
        }
    }
    if (seg == 0 && tid < 128){
        float run = 0.f; float* zp = zs + (size_t)bh*16*128 + tid;
#pragma unroll
        for (int c = 0; c < 16; c++){ float v = zp[c*128]; zp[c*128] = run; run += v; }
    }
}

// ---------- per-chunk output via MFMA ----------
__global__ __launch_bounds__(256) void chunk_out(const u16* __restrict__ qp, const u16* __restrict__ kp,
                                                 const u16* __restrict__ vh, const u16* __restrict__ St,
                                                 const float* __restrict__ zs, u16* __restrict__ y2d)
{
    __shared__ u16 P[128][136];
    __shared__ u16 Vt[64][136];
    __shared__ float denl[128];
    int blk = blockIdx.x, tid = threadIdx.x;
    int lane = tid & 63, w = tid >> 6;
    int m = lane & 15, q = lane >> 4;
    int bh = blk >> 4, c = blk & 15;
    int b = bh >> 4, h = bh & 15, t0 = c*128;
    const u16* qpb = qp + ((size_t)bh*2048 + t0)*128;
    const u16* kpb = kp + ((size_t)bh*2048 + t0)*128;
    const u16* vb  = vh + ((size_t)bh*2048 + t0)*64;
    const u16* Stb = St + (size_t)blk*8192;
    const float* zb = zs + (size_t)blk*128;

#pragma unroll
    for (int it = 0; it < 4; it++){
        int idx = tid + 256*it;
        int t = idx >> 3, d8 = (idx & 7)*8;
        uint4 v = *reinterpret_cast<const uint4*>(&vb[(size_t)t*64 + d8]);
        u32 ww[4] = {v.x, v.y, v.z, v.w};
#pragma unroll
        for (int j = 0; j < 4; j++){
            Vt[d8 + 2*j][t]     = (u16)(ww[j] & 0xFFFFu);
            Vt[d8 + 2*j + 1][t] = (u16)(ww[j] >> 16);
        }
    }
    {
        int row = tid >> 1, half = tid & 1;
        int i = row >> 4;
        for (int s2 = 16*(i + 1) + half*2; s2 < 128; s2 += 4)
            *reinterpret_cast<u32*>(&P[row][s2]) = 0;
    }
    {
        static const unsigned char TIa[36] = {0,1,1,2,2,2,3,3,3,3,4,4,4,4,4,
                                              5,5,5,5,5,5,6,6,6,6,6,6,6,7,7,7,7,7,7,7,7};
        static const unsigned char TJa[36] = {0,0,1,0,1,2,0,1,2,3,0,1,2,3,4,
                                              0,1,2,3,4,5,0,1,2,3,4,5,6,0,1,2,3,4,5,6,7};
        for (int idx = w; idx < 36; idx += 4){
            int i = TIa[idx], j = TJa[idx];
            f32x4 a = {};
            const u16* arow = qpb + (size_t)(i*16 + m)*128 + q*8;
            const u16* brow = kpb + (size_t)(j*16 + m)*128 + q*8;
#pragma unroll
            for (int ks = 0; ks < 4; ks++){
                bf16x8 af = *reinterpret_cast<const bf16x8*>(arow + ks*32);
                bf16x8 bf = *reinterpret_cast<const bf16x8*>(brow + ks*32);
                a = __builtin_amdgcn_mfma_f32_16x16x32_bf16(af, bf, a, 0, 0, 0);
            }
            int scol = j*16 + m;
#pragma unroll
            for (int r = 0; r < 4; r++){
                int trow = i*16 + q*4 + r;
                P[trow][scol] = (scol <= trow) ? f2b(a[r]) : (u16)0;
            }
        }
    }
    __syncthreads();
    if (tid < 128){
        int t = tid;
        float dd = 1e-6f;
        const u32* pr = reinterpret_cast<const u32*>(&P[t][0]);
#pragma unroll
        for (int s2 = 0; s2 < 64; s2++){ u32 u = pr[s2]; dd += b2f_lo(u) + b2f_hi(u); }
        const u16* qrow = qpb + (size_t)t*128;
        for (int f = 0; f < 128; f++) dd += b2f(qrow[f]) * zb[f];
        denl[t] = dd;
    }
    f32x4 acc[2][4] = {};
    for (int ks = 0; ks <= w; ks++){
        bf16x8 af[2], bf4[4];
#pragma unroll
        for (int mt = 0; mt < 2; mt++)
            af[mt] = *reinterpret_cast<const bf16x8*>(&P[32*w + mt*16 + m][ks*32 + q*8]);
#pragma unroll
        for (int nt = 0; nt < 4; nt++)
            bf4[nt] = *reinterpret_cast<const bf16x8*>(&Vt[nt*16 + m][ks*32 + q*8]);
#pragma unroll
        for (int mt = 0; mt < 2; mt++)
#pragma unroll
            for (int nt = 0; nt < 4; nt++)
                acc[mt][nt] = __builtin_amdgcn_mfma_f32_16x16x32_bf16(af[mt], bf4[nt], acc[mt][nt], 0, 0, 0);
    }
#pragma unroll
    for (int ks = 0; ks < 4; ks++){
        bf16x8 af[2], bf4[4];
#pragma unroll
        for (int mt = 0; mt < 2; mt++)
            af[mt] = *reinterpret_cast<const bf16x8*>(qpb + (size_t)(32*w + mt*16 + m)*128 + ks*32 + q*8);
#pragma unroll
        for (int nt = 0; nt < 4; nt++)
            bf4[nt] = *reinterpret_cast<const bf16x8*>(Stb + (size_t)(nt*16 + m)*128 + ks*32 + q*8);
#pragma unroll
        for (int mt = 0; mt < 2; mt++)
#pragma unroll
            for (int nt = 0; nt < 4; nt++)
                acc[mt][nt] = __builtin_amdgcn_mfma_f32_16x16x32_bf16(af[mt], bf4[nt], acc[mt][nt], 0, 0, 0);
    }
    __syncthreads();
#pragma unroll
    for (int mt = 0; mt < 2; mt++){
#pragma unroll
        for (int nt = 0; nt < 4; nt++){
#pragma unroll
            for (int r = 0; r < 4; r++){
                int t = 32*w + mt*16 + q*4 + r;
                int d = nt*16 + m;
                y2d[((size_t)b*2048 + t0 + t)*1024 + h*64 + d] = f2b(acc[mt][nt][r] / denl[t]);
            }
        }
    }
}

extern "C" void kernel_launch(void* const* d_in, const int* in_sizes, int n_in,
                              void* d_out, int out_size, void* d_ws, size_t ws_size,
                              hipStream_t stream)
{
    (void)in_sizes; (void)n_in; (void)out_size; (void)ws_size;
    const float* x  = (const float*)d_in[0];
    const float* Wq = (const float*)d_in[1];
    const float* Wk = (const float*)d_in[2];
    const float* Wv = (const float*)d_in[3];
    const float* Wo = (const float*)d_in[4];
    const float* Wf = (const float*)d_in[5];
    float* out = (float*)d_out;
    char* ws = (char*)d_ws;

    // workspace layout (lifetime-aliased, ~137 MiB)
    u16*   qh  = (u16*)  (ws + 0);           // 16MB bf16 (B,H,T,HD), dead after featmap(q)
    u16*   Sa  = (u16*)  (ws + 0);           // alias qh: chunk S^T raw bf16, 16MB
    u16*   kh  = (u16*)  (ws + 16777216);    // 16MB bf16, dead after featmap(k)
    u16*   Sbp = (u16*)  (ws + 16777216);    // alias kh: prefix S^T bf16, 16MB
    u16*   vh  = (u16*)  (ws + 33554432);    // 16MB bf16 (B,H,T,HD)
    u16*   qp  = (u16*)  (ws + 50331648);    // 32MB bf16 (B,H,T,NF)
    u16*   kp  = (u16*)  (ws + 83886080);    // 32MB bf16
    u16*   y2d = (u16*)  (ws + 117440512);   // 16MB bf16 (B*T, H*HD)
    u16*   WTq = (u16*)  (ws + 134217728);   // 2MB bf16 each
    u16*   WTk = (u16*)  (ws + 136314880);
    u16*   WTv = (u16*)  (ws + 138412032);
    u16*   WTo = (u16*)  (ws + 140509184);
    float* zs  = (float*)(ws + 142606336);   // (B,H,NC,NF) fp32, 0.5MB

    dim3 tgrid(16, 16);
    transpose1024<<<tgrid, 256, 0, stream>>>(Wq, WTq);
    transpose1024<<<tgrid, 256, 0, stream>>>(Wk, WTk);
    transpose1024<<<tgrid, 256, 0, stream>>>(Wv, WTv);
    transpose1024<<<tgrid, 256, 0, stream>>>(Wo, WTo);

    dim3 ggrid(64, 8);
    gemm128<1,1><<<ggrid, 256, 0, stream>>>(x, WTq, nullptr, qh);
    gemm128<1,1><<<ggrid, 256, 0, stream>>>(x, WTk, nullptr, kh);
    gemm128<1,1><<<ggrid, 256, 0, stream>>>(x, WTv, nullptr, vh);

    featmap_mfma<<<1024, 256, 0, stream>>>(qh, Wf, qp);
    featmap_mfma<<<1024, 256, 0, stream>>>(kh, Wf, kp);

    chunk_sum<<<1024, 256, 0, stream>>>(kp, vh, Sa, zs);
    prefix_chunks<<<dim3(64, 8), 256, 0, stream>>>(Sa, Sbp, zs);
    chunk_out<<<1024, 256, 0, stream>>>(qp, kp, vh, Sbp, zs, y2d);

    gemm128<2,0><<<ggrid, 256, 0, stream>>>(y2d, WTo, out, nullptr);
}

// Round 7
// 350.316 us; speedup vs baseline: 2.8768x; 1.1493x over previous
//
#include <hip/hip_runtime.h>
#include <hip/hip_bf16.h>

typedef unsigned int u32;
typedef unsigned short u16;
typedef __bf16 bf16x8 __attribute__((ext_vector_type(8)));
typedef float f32x4 __attribute__((ext_vector_type(4)));

// ---------- bf16 bit helpers ----------
__device__ __forceinline__ float b2f(u16 s){ union{u32 x; float f;} c; c.x = ((u32)s) << 16; return c.f; }
__device__ __forceinline__ float b2f_lo(u32 u){ union{u32 x; float f;} c; c.x = u << 16; return c.f; }
__device__ __forceinline__ float b2f_hi(u32 u){ union{u32 x; float f;} c; c.x = u & 0xFFFF0000u; return c.f; }
__device__ __forceinline__ u16 f2b(float f){
    union{float f; u32 u;} c; c.f = f;
    u32 r = c.u + 0x7FFFu + ((c.u >> 16) & 1u);
    return (u16)(r >> 16);
}
__device__ __forceinline__ u32 pk(float lo, float hi){
    return (u32)f2b(lo) | ((u32)f2b(hi) << 16);
}
// async global->LDS, 16B per lane (HW: wave-uniform base + lane*16)
__device__ __forceinline__ void gl_lds16(const u16* g, u16* l){
    __builtin_amdgcn_global_load_lds(
        (const __attribute__((address_space(1))) void*)g,
        (__attribute__((address_space(3))) void*)l, 16, 0, 0);
}

// Problem constants: B=4, T=2048, D=1024, H=16, HD=64, NF=128, chunk C=128, NC=16
// All inputs FLOAT32; OUTPUT is FLOAT32.

// ---------- fp32 -> bf16 bulk convert (x) ----------
__global__ __launch_bounds__(256) void tobf16(const float* __restrict__ in, u16* __restrict__ out)
{
    size_t i = ((size_t)blockIdx.x * 256 + threadIdx.x) * 8;
    float4 a = *reinterpret_cast<const float4*>(in + i);
    float4 b = *reinterpret_cast<const float4*>(in + i + 4);
    uint4 v; v.x = pk(a.x, a.y); v.y = pk(a.z, a.w); v.z = pk(b.x, b.y); v.w = pk(b.z, b.w);
    *reinterpret_cast<uint4*>(out + i) = v;
}

// ---------- 1024x1024 transpose + fp32->bf16 convert (weights -> W^T bf16) ----------
__global__ __launch_bounds__(256) void transpose1024(const float* __restrict__ in, u16* __restrict__ out)
{
    __shared__ u16 tile[64][72];
    int kb = blockIdx.x * 64, nb = blockIdx.y * 64, tid = threadIdx.x;
#pragma unroll
    for (int i = 0; i < 2; i++){
        int idx = tid + 256*i; int r = idx >> 3; int c8 = (idx & 7) * 8;
        const float* p = &in[(size_t)(kb + r)*1024 + nb + c8];
        float4 lo = *reinterpret_cast<const float4*>(p);
        float4 hi = *reinterpret_cast<const float4*>(p + 4);
        uint4 v;
        v.x = pk(lo.x, lo.y); v.y = pk(lo.z, lo.w);
        v.z = pk(hi.x, hi.y); v.w = pk(hi.z, hi.w);
        *reinterpret_cast<uint4*>(&tile[r][c8]) = v;
    }
    __syncthreads();
#pragma unroll
    for (int i = 0; i < 2; i++){
        int idx = tid + 256*i; int c = idx >> 3; int r8 = (idx & 7) * 8;
        u32 w[4];
#pragma unroll
        for (int j = 0; j < 4; j++)
            w[j] = (u32)tile[r8 + 2*j][c] | ((u32)tile[r8 + 2*j + 1][c] << 16);
        uint4 v; v.x = w[0]; v.y = w[1]; v.z = w[2]; v.w = w[3];
        *reinterpret_cast<uint4*>(&out[(size_t)(nb + c)*1024 + kb + r8]) = v;
    }
}

// ---------- async MFMA bf16 GEMM (m97 structure): C[8192,N] = A[8192,1024] * W, BT = bf16 W^T ----------
// MODE 2: write fp32, plain row-major (final output), N=1024
// MODE 3: fused QKV: N=3072, write bf16 remapped (which,B,H,T,HD) into outh base
template<int MODE>
__global__ __launch_bounds__(256) void gemm_async(const u16* __restrict__ A, const u16* __restrict__ BT,
                                                  float* __restrict__ outf, u16* __restrict__ outh)
{
    __shared__ u16 As[128][32];   // unpadded: global_load_lds needs contiguous lane order
    __shared__ u16 Bs[128][32];
    int tid = threadIdx.x, lane = tid & 63, w = tid >> 6;
    int m0 = blockIdx.x * 128, n0 = blockIdx.y * 128;
    int wm = (w >> 1) * 64, wn = (w & 1) * 64;
    int fr = lane & 15, fk = (lane >> 4) * 8;
    f32x4 acc[4][4] = {};
    // staging geometry: wave w, inst j in {0,1} -> rows 32w+16j+lane/4, col (lane&3)*8
    int r0 = 32*w + (lane >> 2), c0 = (lane & 3) * 8;
    const u16* Ag0 = A  + (size_t)(m0 + r0)*1024 + c0;
    const u16* Ag1 = A  + (size_t)(m0 + r0 + 16)*1024 + c0;
    const u16* Bg0 = BT + (size_t)(n0 + r0)*1024 + c0;
    const u16* Bg1 = BT + (size_t)(n0 + r0 + 16)*1024 + c0;
    u16* Al0 = &As[r0][c0];      u16* Al1 = &As[r0 + 16][c0];
    u16* Bl0 = &Bs[r0][c0];      u16* Bl1 = &Bs[r0 + 16][c0];
    for (int k0 = 0; k0 < 1024; k0 += 32){
        __syncthreads();                       // protect LDS from previous iteration's readers
        gl_lds16(Ag0 + k0, Al0);
        gl_lds16(Ag1 + k0, Al1);
        gl_lds16(Bg0 + k0, Bl0);
        gl_lds16(Bg1 + k0, Bl1);
        __syncthreads();                       // drains vmcnt, LDS populated
        bf16x8 af[4], bf[4];
#pragma unroll
        for (int i = 0; i < 4; i++){
            af[i] = *reinterpret_cast<const bf16x8*>(&As[wm + i*16 + fr][fk]);
            bf[i] = *reinterpret_cast<const bf16x8*>(&Bs[wn + i*16 + fr][fk]);
        }
#pragma unroll
        for (int i = 0; i < 4; i++)
#pragma unroll
            for (int j = 0; j < 4; j++)
                acc[i][j] = __builtin_amdgcn_mfma_f32_16x16x32_bf16(af[i], bf[j], acc[i][j], 0, 0, 0);
    }
#pragma unroll
    for (int i = 0; i < 4; i++){
        int row0 = m0 + wm + i*16 + ((lane >> 4) << 2);
#pragma unroll
        for (int j = 0; j < 4; j++){
            int col = n0 + wn + j*16 + fr;
#pragma unroll
            for (int r = 0; r < 4; r++){
                float val = acc[i][j][r];
                int row = row0 + r;
                if (MODE == 2){
                    outf[(size_t)row*1024 + col] = val;
                } else {
                    int which = col >> 10, colw = col & 1023;
                    int h = colw >> 6, d = colw & 63;
                    int bb = row >> 11, t = row & 2047;
                    outh[(size_t)which*8388608 + (((size_t)(bb*16 + h))*2048 + t)*64 + d] = f2b(val);
                }
            }
        }
    }
}

// ---------- FAVOR+ feature map via MFMA: phi = exp(x.Wf - 0.5||x||^2)/sqrt(NF) ----------
__global__ __launch_bounds__(256) void featmap_mfma(const u16* __restrict__ xh, const float* __restrict__ Wf,
                                                    u16* __restrict__ xp)
{
    __shared__ u16 Xl[128][72];
    __shared__ u16 Wft[128][72];
    __shared__ float sqp[128][8];
    __shared__ float sql[128];
    int tid = threadIdx.x;
    int lane = tid & 63, w = tid >> 6;
    int m = lane & 15, q = lane >> 4;
    const u16* xb = xh + (size_t)blockIdx.x * 128 * 64;
#pragma unroll
    for (int it = 0; it < 4; it++){
        int idx = tid + 256*it;
        int row = idx >> 3, c8 = (idx & 7) * 8;
        uint4 v = *reinterpret_cast<const uint4*>(xb + (size_t)row*64 + c8);
        *reinterpret_cast<uint4*>(&Xl[row][c8]) = v;
        u32 ww[4] = {v.x, v.y, v.z, v.w};
        float s = 0.f;
#pragma unroll
        for (int j = 0; j < 4; j++){
            float a = b2f_lo(ww[j]), bb = b2f_hi(ww[j]);
            s += a*a + bb*bb;
        }
        sqp[row][idx & 7] = s;
    }
#pragma unroll
    for (int it = 0; it < 8; it++){
        int idx = tid + 256*it;
        int d = idx >> 5, f4 = (idx & 31) * 4;
        float4 v = *reinterpret_cast<const float4*>(Wf + d*128 + f4);
        Wft[f4+0][d] = f2b(v.x); Wft[f4+1][d] = f2b(v.y);
        Wft[f4+2][d] = f2b(v.z); Wft[f4+3][d] = f2b(v.w);
    }
    __syncthreads();
    if (tid < 128){
        float s = 0.f;
#pragma unroll
        for (int j = 0; j < 8; j++) s += sqp[tid][j];
        sql[tid] = s;
    }
    f32x4 acc[2][8] = {};
#pragma unroll
    for (int ks = 0; ks < 2; ks++){
        bf16x8 af[2], bf[8];
#pragma unroll
        for (int mt = 0; mt < 2; mt++)
            af[mt] = *reinterpret_cast<const bf16x8*>(&Xl[32*w + mt*16 + m][ks*32 + q*8]);
#pragma unroll
        for (int nt = 0; nt < 8; nt++)
            bf[nt] = *reinterpret_cast<const bf16x8*>(&Wft[nt*16 + m][ks*32 + q*8]);
#pragma unroll
        for (int mt = 0; mt < 2; mt++)
#pragma unroll
            for (int nt = 0; nt < 8; nt++)
                acc[mt][nt] = __builtin_amdgcn_mfma_f32_16x16x32_bf16(af[mt], bf[nt], acc[mt][nt], 0, 0, 0);
    }
    __syncthreads();
    const float c = 0.08838834764831845f; // 1/sqrt(128)
    u16* xpb = xp + (size_t)blockIdx.x * 128 * 128;
#pragma unroll
    for (int mt = 0; mt < 2; mt++){
#pragma unroll
        for (int r = 0; r < 4; r++){
            int t = 32*w + mt*16 + q*4 + r;
            float hs = 0.5f * sql[t];
#pragma unroll
            for (int nt = 0; nt < 8; nt++){
                int f = nt*16 + m;
                xpb[(size_t)t*128 + f] = f2b(__expf(fminf(acc[mt][nt][r] - hs, 60.f)) * c);
            }
        }
    }
}

// ---------- per-chunk KV summaries: S_c^T[d][f] (bf16), z_c = colsum(Kp_c) ----------
__global__ __launch_bounds__(256) void chunk_sum(const u16* __restrict__ kp, const u16* __restrict__ vh,
                                                 u16* __restrict__ Sa, float* __restrict__ zs)
{
    __shared__ u16 Kl[128][128];
    __shared__ u16 Vl[128][64];
    int blk = blockIdx.x, tid = threadIdx.x;
    int bh = blk >> 4, c = blk & 15;
    const u16* kpb = kp + ((size_t)bh*2048 + c*128)*128;
    const u16* vb  = vh + ((size_t)bh*2048 + c*128)*64;
#pragma unroll
    for (int i = 0; i < 8; i++){ int idx = tid + 256*i; int t = idx >> 4, f8 = (idx & 15)*8;
        *reinterpret_cast<uint4*>(&Kl[t][f8]) = *reinterpret_cast<const uint4*>(&kpb[(size_t)t*128 + f8]); }
#pragma unroll
    for (int i = 0; i < 4; i++){ int idx = tid + 256*i; int t = idx >> 3, d8 = (idx & 7)*8;
        *reinterpret_cast<uint4*>(&Vl[t][d8]) = *reinterpret_cast<const uint4*>(&vb[(size_t)t*64 + d8]); }
    __syncthreads();
    int d = tid & 63, fq = tid >> 6;
    float acc[32];
#pragma unroll
    for (int i = 0; i < 32; i++) acc[i] = 0.f;
    for (int t = 0; t < 128; t++){
        float vd = b2f(Vl[t][d]);
        const u32* kr = reinterpret_cast<const u32*>(&Kl[t][fq*32]);
#pragma unroll
        for (int i = 0; i < 16; i++){
            u32 u = kr[i];
            acc[2*i]     += b2f_lo(u) * vd;
            acc[2*i + 1] += b2f_hi(u) * vd;
        }
    }
    u16* Sb = Sa + (size_t)blk*8192 + (size_t)d*128 + fq*32;
#pragma unroll
    for (int v4 = 0; v4 < 4; v4++){
        uint4 o;
        o.x = pk(acc[v4*8+0], acc[v4*8+1]);
        o.y = pk(acc[v4*8+2], acc[v4*8+3]);
        o.z = pk(acc[v4*8+4], acc[v4*8+5]);
        o.w = pk(acc[v4*8+6], acc[v4*8+7]);
        *reinterpret_cast<uint4*>(Sb + v4*8) = o;
    }
    if (tid < 128){
        float z = 0.f;
        for (int t = 0; t < 128; t++) z += b2f(Kl[t][tid]);
        zs[(size_t)blk*128 + tid] = z;
    }
}

// ---------- exclusive prefix over the 16 chunks (per bh), bf16 in/out ----------
__global__ __launch_bounds__(256) void prefix_chunks(const u16* __restrict__ Sa, u16* __restrict__ Sb,
                                                     float* __restrict__ zs)
{
    int bh = blockIdx.x, seg = blockIdx.y, tid = threadIdx.x;
    const u16* src = Sa + (size_t)bh*16*8192;
    u16*       dst = Sb + (size_t)bh*16*8192;
#pragma unroll
    for (int it = 0; it < 4; it++){
        int e = seg*1024 + it*256 + tid;
        float run = 0.f;
#pragma unroll
        for (int c = 0; c < 16; c++){
            float v = b2f(src[(size_t)c*8192 + e]);
            dst[(size_t)c*8192 + e] = f2b(run);
            run += v;
        }
    }
    if (seg == 0 && tid < 128){
        float run = 0.f; float* zp = zs + (size_t)bh*16*128 + tid;
#pragma unroll
        for (int c = 0; c < 16; c++){ float v = zp[c*128]; zp[c*128] = run; run += v; }
    }
}

// ---------- per-chunk output via MFMA; denominator fused as extra MFMA B-tiles ----------
__global__ __launch_bounds__(256) void chunk_out(const u16* __restrict__ qp, const u16* __restrict__ kp,
                                                 const u16* __restrict__ vh, const u16* __restrict__ St,
                                                 const float* __restrict__ zs, u16* __restrict__ y2d)
{
    __shared__ u16 P[128][136];
    __shared__ u16 Vt[64][136];
    __shared__ u16 zl[128];
    int blk = blockIdx.x, tid = threadIdx.x;
    int lane = tid & 63, w = tid >> 6;
    int m = lane & 15, q = lane >> 4;
    int bh = blk >> 4, c = blk & 15;
    int b = bh >> 4, h = bh & 15, t0 = c*128;
    const u16* qpb = qp + ((size_t)bh*2048 + t0)*128;
    const u16* kpb = kp + ((size_t)bh*2048 + t0)*128;
    const u16* vb  = vh + ((size_t)bh*2048 + t0)*64;
    const u16* Stb = St + (size_t)blk*8192;

    if (tid < 128) zl[tid] = f2b(zs[(size_t)blk*128 + tid]);
    // stage V transposed
#pragma unroll
    for (int it = 0; it < 4; it++){
        int idx = tid + 256*it;
        int t = idx >> 3, d8 = (idx & 7)*8;
        uint4 v = *reinterpret_cast<const uint4*>(&vb[(size_t)t*64 + d8]);
        u32 ww[4] = {v.x, v.y, v.z, v.w};
#pragma unroll
        for (int j = 0; j < 4; j++){
            Vt[d8 + 2*j][t]     = (u16)(ww[j] & 0xFFFFu);
            Vt[d8 + 2*j + 1][t] = (u16)(ww[j] >> 16);
        }
    }
    // zero strict-upper tiles of P
    {
        int row = tid >> 1, half = tid & 1;
        int i = row >> 4;
        for (int s2 = 16*(i + 1) + half*2; s2 < 128; s2 += 4)
            *reinterpret_cast<u32*>(&P[row][s2]) = 0;
    }
    // phase A: QK^T lower-triangle tiles
    {
        static const unsigned char TIa[36] = {0,1,1,2,2,2,3,3,3,3,4,4,4,4,4,
                                              5,5,5,5,5,5,6,6,6,6,6,6,6,7,7,7,7,7,7,7,7};
        static const unsigned char TJa[36] = {0,0,1,0,1,2,0,1,2,3,0,1,2,3,4,
                                              0,1,2,3,4,5,0,1,2,3,4,5,6,0,1,2,3,4,5,6,7};
        for (int idx = w; idx < 36; idx += 4){
            int i = TIa[idx], j = TJa[idx];
            f32x4 a = {};
            const u16* arow = qpb + (size_t)(i*16 + m)*128 + q*8;
            const u16* brow = kpb + (size_t)(j*16 + m)*128 + q*8;
#pragma unroll
            for (int ks = 0; ks < 4; ks++){
                bf16x8 af = *reinterpret_cast<const bf16x8*>(arow + ks*32);
                bf16x8 bf = *reinterpret_cast<const bf16x8*>(brow + ks*32);
                a = __builtin_amdgcn_mfma_f32_16x16x32_bf16(af, bf, a, 0, 0, 0);
            }
            int scol = j*16 + m;
#pragma unroll
            for (int r = 0; r < 4; r++){
                int trow = i*16 + q*4 + r;
                P[trow][scol] = (scol <= trow) ? f2b(a[r]) : (u16)0;
            }
        }
    }
    __syncthreads();
    // phase B: O = P.V + Qp.S_in ; den = P.1 + Qp.z (extra B-tiles, per-lane aligned with acc rows)
    f32x4 acc[2][4] = {};
    f32x4 accd[2] = {};
    bf16x8 ones;
#pragma unroll
    for (int i = 0; i < 8; i++) ones[i] = (__bf16)1.0f;
    for (int ks = 0; ks <= w; ks++){
        bf16x8 af[2], bf4[4];
#pragma unroll
        for (int mt = 0; mt < 2; mt++)
            af[mt] = *reinterpret_cast<const bf16x8*>(&P[32*w + mt*16 + m][ks*32 + q*8]);
#pragma unroll
        for (int nt = 0; nt < 4; nt++)
            bf4[nt] = *reinterpret_cast<const bf16x8*>(&Vt[nt*16 + m][ks*32 + q*8]);
#pragma unroll
        for (int mt = 0; mt < 2; mt++){
#pragma unroll
            for (int nt = 0; nt < 4; nt++)
                acc[mt][nt] = __builtin_amdgcn_mfma_f32_16x16x32_bf16(af[mt], bf4[nt], acc[mt][nt], 0, 0, 0);
            accd[mt] = __builtin_amdgcn_mfma_f32_16x16x32_bf16(af[mt], ones, accd[mt], 0, 0, 0);
        }
    }
#pragma unroll
    for (int ks = 0; ks < 4; ks++){
        bf16x8 af[2], bf4[4];
        bf16x8 zf = *reinterpret_cast<const bf16x8*>(&zl[ks*32 + q*8]);
#pragma unroll
        for (int mt = 0; mt < 2; mt++)
            af[mt] = *reinterpret_cast<const bf16x8*>(qpb + (size_t)(32*w + mt*16 + m)*128 + ks*32 + q*8);
#pragma unroll
        for (int nt = 0; nt < 4; nt++)
            bf4[nt] = *reinterpret_cast<const bf16x8*>(Stb + (size_t)(nt*16 + m)*128 + ks*32 + q*8);
#pragma unroll
        for (int mt = 0; mt < 2; mt++){
#pragma unroll
            for (int nt = 0; nt < 4; nt++)
                acc[mt][nt] = __builtin_amdgcn_mfma_f32_16x16x32_bf16(af[mt], bf4[nt], acc[mt][nt], 0, 0, 0);
            accd[mt] = __builtin_amdgcn_mfma_f32_16x16x32_bf16(af[mt], zf, accd[mt], 0, 0, 0);
        }
    }
    // epilogue (no barrier needed: everything per-lane)
#pragma unroll
    for (int mt = 0; mt < 2; mt++){
#pragma unroll
        for (int nt = 0; nt < 4; nt++){
#pragma unroll
            for (int r = 0; r < 4; r++){
                int t = 32*w + mt*16 + q*4 + r;
                int d = nt*16 + m;
                float den = accd[mt][r] + 1e-6f;
                y2d[((size_t)b*2048 + t0 + t)*1024 + h*64 + d] = f2b(acc[mt][nt][r] / den);
            }
        }
    }
}

extern "C" void kernel_launch(void* const* d_in, const int* in_sizes, int n_in,
                              void* d_out, int out_size, void* d_ws, size_t ws_size,
                              hipStream_t stream)
{
    (void)in_sizes; (void)n_in; (void)out_size; (void)ws_size;
    const float* x  = (const float*)d_in[0];
    const float* Wq = (const float*)d_in[1];
    const float* Wk = (const float*)d_in[2];
    const float* Wv = (const float*)d_in[3];
    const float* Wo = (const float*)d_in[4];
    const float* Wf = (const float*)d_in[5];
    float* out = (float*)d_out;
    char* ws = (char*)d_ws;

    // workspace layout (lifetime-aliased, ~136.5 MiB)
    u16*   xh    = (u16*)  (ws + 0);           // 16MB x bf16 (dead after QKV gemm)
    u16*   Sa    = (u16*)  (ws + 0);           // alias xh: chunk S^T raw bf16
    u16*   qh    = (u16*)  (ws + 16777216);    // 16MB (dead after featmap q)
    u16*   Sbp   = (u16*)  (ws + 16777216);    // alias qh: prefix S^T
    u16*   kh    = (u16*)  (ws + 33554432);    // 16MB (dead after featmap k)
    u16*   y2d   = (u16*)  (ws + 33554432);    // alias kh
    u16*   vh    = (u16*)  (ws + 50331648);    // 16MB
    u16*   qp    = (u16*)  (ws + 67108864);    // 32MB
    u16*   kp    = (u16*)  (ws + 100663296);   // 32MB
    u16*   WTqkv = (u16*)  (ws + 134217728);   // 6MB (3 x 1024x1024 bf16)
    u16*   WTo   = (u16*)  (ws + 140509184);   // 2MB
    float* zs    = (float*)(ws + 142606336);   // 0.5MB

    tobf16<<<4096, 256, 0, stream>>>(x, xh);

    dim3 tgrid(16, 16);
    transpose1024<<<tgrid, 256, 0, stream>>>(Wq, WTqkv);
    transpose1024<<<tgrid, 256, 0, stream>>>(Wk, WTqkv + 1048576);
    transpose1024<<<tgrid, 256, 0, stream>>>(Wv, WTqkv + 2097152);
    transpose1024<<<tgrid, 256, 0, stream>>>(Wo, WTo);

    // fused QKV: writes qh, kh, vh (contiguous 16MB blocks starting at qh)
    gemm_async<3><<<dim3(64, 24), 256, 0, stream>>>(xh, WTqkv, nullptr, qh);

    featmap_mfma<<<1024, 256, 0, stream>>>(qh, Wf, qp);
    featmap_mfma<<<1024, 256, 0, stream>>>(kh, Wf, kp);

    chunk_sum<<<1024, 256, 0, stream>>>(kp, vh, Sa, zs);
    prefix_chunks<<<dim3(64, 8), 256, 0, stream>>>(Sa, Sbp, zs);
    chunk_out<<<1024, 256, 0, stream>>>(qp, kp, vh, Sbp, zs, y2d);

    gemm_async<2><<<dim3(64, 8), 256, 0, stream>>>(y2d, WTo, out, nullptr);
}

// Round 8
// 301.316 us; speedup vs baseline: 3.3447x; 1.1626x over previous
//
#include <hip/hip_runtime.h>
#include <hip/hip_bf16.h>

typedef unsigned int u32;
typedef unsigned short u16;
typedef __bf16 bf16x8 __attribute__((ext_vector_type(8)));
typedef float f32x4 __attribute__((ext_vector_type(4)));

// ---------- bf16 bit helpers ----------
__device__ __forceinline__ float b2f(u16 s){ union{u32 x; float f;} c; c.x = ((u32)s) << 16; return c.f; }
__device__ __forceinline__ float b2f_lo(u32 u){ union{u32 x; float f;} c; c.x = u << 16; return c.f; }
__device__ __forceinline__ float b2f_hi(u32 u){ union{u32 x; float f;} c; c.x = u & 0xFFFF0000u; return c.f; }
__device__ __forceinline__ u16 f2b(float f){
    union{float f; u32 u;} c; c.f = f;
    u32 r = c.u + 0x7FFFu + ((c.u >> 16) & 1u);
    return (u16)(r >> 16);
}
__device__ __forceinline__ u32 pk(float lo, float hi){
    return (u32)f2b(lo) | ((u32)f2b(hi) << 16);
}
// async global->LDS, 16B per lane (HW: wave-uniform base + lane*16)
__device__ __forceinline__ void gl_lds16(const u16* g, u16* l){
    __builtin_amdgcn_global_load_lds(
        (const __attribute__((address_space(1))) void*)g,
        (__attribute__((address_space(3))) void*)l, 16, 0, 0);
}

// Problem constants: B=4, T=2048, D=1024, H=16, HD=64, NF=128, chunk C=128, NC=16
// All inputs FLOAT32; OUTPUT is FLOAT32.

// ---------- fp32 -> bf16 bulk convert (x) ----------
__global__ __launch_bounds__(256) void tobf16(const float* __restrict__ in, u16* __restrict__ out)
{
    size_t i = ((size_t)blockIdx.x * 256 + threadIdx.x) * 8;
    float4 a = *reinterpret_cast<const float4*>(in + i);
    float4 b = *reinterpret_cast<const float4*>(in + i + 4);
    uint4 v; v.x = pk(a.x, a.y); v.y = pk(a.z, a.w); v.z = pk(b.x, b.y); v.w = pk(b.z, b.w);
    *reinterpret_cast<uint4*>(out + i) = v;
}

// ---------- all 4 weight transposes (+fp32->bf16) in one dispatch ----------
__global__ __launch_bounds__(256) void transpose_all(const float* __restrict__ Wq, const float* __restrict__ Wk,
                                                     const float* __restrict__ Wv, const float* __restrict__ Wo,
                                                     u16* __restrict__ WTqkv, u16* __restrict__ WTo)
{
    const float* in; u16* out;
    switch (blockIdx.z){
        case 0:  in = Wq; out = WTqkv;           break;
        case 1:  in = Wk; out = WTqkv + 1048576; break;
        case 2:  in = Wv; out = WTqkv + 2097152; break;
        default: in = Wo; out = WTo;             break;
    }
    __shared__ u16 tile[64][72];
    int kb = blockIdx.x * 64, nb = blockIdx.y * 64, tid = threadIdx.x;
#pragma unroll
    for (int i = 0; i < 2; i++){
        int idx = tid + 256*i; int r = idx >> 3; int c8 = (idx & 7) * 8;
        const float* p = &in[(size_t)(kb + r)*1024 + nb + c8];
        float4 lo = *reinterpret_cast<const float4*>(p);
        float4 hi = *reinterpret_cast<const float4*>(p + 4);
        uint4 v;
        v.x = pk(lo.x, lo.y); v.y = pk(lo.z, lo.w);
        v.z = pk(hi.x, hi.y); v.w = pk(hi.z, hi.w);
        *reinterpret_cast<uint4*>(&tile[r][c8]) = v;
    }
    __syncthreads();
#pragma unroll
    for (int i = 0; i < 2; i++){
        int idx = tid + 256*i; int c = idx >> 3; int r8 = (idx & 7) * 8;
        u32 w[4];
#pragma unroll
        for (int j = 0; j < 4; j++)
            w[j] = (u32)tile[r8 + 2*j][c] | ((u32)tile[r8 + 2*j + 1][c] << 16);
        uint4 v; v.x = w[0]; v.y = w[1]; v.z = w[2]; v.w = w[3];
        *reinterpret_cast<uint4*>(&out[(size_t)(nb + c)*1024 + kb + r8]) = v;
    }
}

// ---------- async MFMA bf16 GEMM (m97 structure): C[8192,N] = A[8192,1024] * W, BT = bf16 W^T ----------
// MODE 2: write fp32, plain row-major (final output), N=1024
// MODE 3: fused QKV: N=3072, write bf16 remapped (which,B,H,T,HD) into outh base
template<int MODE>
__global__ __launch_bounds__(256) void gemm_async(const u16* __restrict__ A, const u16* __restrict__ BT,
                                                  float* __restrict__ outf, u16* __restrict__ outh)
{
    __shared__ u16 As[128][32];   // unpadded: global_load_lds needs contiguous lane order
    __shared__ u16 Bs[128][32];
    int tid = threadIdx.x, lane = tid & 63, w = tid >> 6;
    int m0 = blockIdx.x * 128, n0 = blockIdx.y * 128;
    int wm = (w >> 1) * 64, wn = (w & 1) * 64;
    int fr = lane & 15, fk = (lane >> 4) * 8;
    f32x4 acc[4][4] = {};
    int r0 = 32*w + (lane >> 2), c0 = (lane & 3) * 8;
    const u16* Ag0 = A  + (size_t)(m0 + r0)*1024 + c0;
    const u16* Ag1 = A  + (size_t)(m0 + r0 + 16)*1024 + c0;
    const u16* Bg0 = BT + (size_t)(n0 + r0)*1024 + c0;
    const u16* Bg1 = BT + (size_t)(n0 + r0 + 16)*1024 + c0;
    u16* Al0 = &As[r0][c0];      u16* Al1 = &As[r0 + 16][c0];
    u16* Bl0 = &Bs[r0][c0];      u16* Bl1 = &Bs[r0 + 16][c0];
    for (int k0 = 0; k0 < 1024; k0 += 32){
        __syncthreads();
        gl_lds16(Ag0 + k0, Al0);
        gl_lds16(Ag1 + k0, Al1);
        gl_lds16(Bg0 + k0, Bl0);
        gl_lds16(Bg1 + k0, Bl1);
        __syncthreads();
        bf16x8 af[4], bf[4];
#pragma unroll
        for (int i = 0; i < 4; i++){
            af[i] = *reinterpret_cast<const bf16x8*>(&As[wm + i*16 + fr][fk]);
            bf[i] = *reinterpret_cast<const bf16x8*>(&Bs[wn + i*16 + fr][fk]);
        }
#pragma unroll
        for (int i = 0; i < 4; i++)
#pragma unroll
            for (int j = 0; j < 4; j++)
                acc[i][j] = __builtin_amdgcn_mfma_f32_16x16x32_bf16(af[i], bf[j], acc[i][j], 0, 0, 0);
    }
#pragma unroll
    for (int i = 0; i < 4; i++){
        int row0 = m0 + wm + i*16 + ((lane >> 4) << 2);
#pragma unroll
        for (int j = 0; j < 4; j++){
            int col = n0 + wn + j*16 + fr;
#pragma unroll
            for (int r = 0; r < 4; r++){
                float val = acc[i][j][r];
                int row = row0 + r;
                if (MODE == 2){
                    outf[(size_t)row*1024 + col] = val;
                } else {
                    int which = col >> 10, colw = col & 1023;
                    int h = colw >> 6, d = colw & 63;
                    int bb = row >> 11, t = row & 2047;
                    outh[(size_t)which*8388608 + (((size_t)(bb*16 + h))*2048 + t)*64 + d] = f2b(val);
                }
            }
        }
    }
}

// ---------- FAVOR+ feature map via MFMA (q path): phi = exp(x.Wf - 0.5||x||^2)/sqrt(NF) ----------
__global__ __launch_bounds__(256) void featmap_mfma(const u16* __restrict__ xh, const float* __restrict__ Wf,
                                                    u16* __restrict__ xp)
{
    __shared__ u16 Xl[128][72];
    __shared__ u16 Wft[128][72];
    __shared__ float sqp[128][8];
    __shared__ float sql[128];
    int tid = threadIdx.x;
    int lane = tid & 63, w = tid >> 6;
    int m = lane & 15, q = lane >> 4;
    const u16* xb = xh + (size_t)blockIdx.x * 128 * 64;
#pragma unroll
    for (int it = 0; it < 4; it++){
        int idx = tid + 256*it;
        int row = idx >> 3, c8 = (idx & 7) * 8;
        uint4 v = *reinterpret_cast<const uint4*>(xb + (size_t)row*64 + c8);
        *reinterpret_cast<uint4*>(&Xl[row][c8]) = v;
        u32 ww[4] = {v.x, v.y, v.z, v.w};
        float s = 0.f;
#pragma unroll
        for (int j = 0; j < 4; j++){
            float a = b2f_lo(ww[j]), bb = b2f_hi(ww[j]);
            s += a*a + bb*bb;
        }
        sqp[row][idx & 7] = s;
    }
#pragma unroll
    for (int it = 0; it < 8; it++){
        int idx = tid + 256*it;
        int d = idx >> 5, f4 = (idx & 31) * 4;
        float4 v = *reinterpret_cast<const float4*>(Wf + d*128 + f4);
        Wft[f4+0][d] = f2b(v.x); Wft[f4+1][d] = f2b(v.y);
        Wft[f4+2][d] = f2b(v.z); Wft[f4+3][d] = f2b(v.w);
    }
    __syncthreads();
    if (tid < 128){
        float s = 0.f;
#pragma unroll
        for (int j = 0; j < 8; j++) s += sqp[tid][j];
        sql[tid] = s;
    }
    f32x4 acc[2][8] = {};
#pragma unroll
    for (int ks = 0; ks < 2; ks++){
        bf16x8 af[2], bf[8];
#pragma unroll
        for (int mt = 0; mt < 2; mt++)
            af[mt] = *reinterpret_cast<const bf16x8*>(&Xl[32*w + mt*16 + m][ks*32 + q*8]);
#pragma unroll
        for (int nt = 0; nt < 8; nt++)
            bf[nt] = *reinterpret_cast<const bf16x8*>(&Wft[nt*16 + m][ks*32 + q*8]);
#pragma unroll
        for (int mt = 0; mt < 2; mt++)
#pragma unroll
            for (int nt = 0; nt < 8; nt++)
                acc[mt][nt] = __builtin_amdgcn_mfma_f32_16x16x32_bf16(af[mt], bf[nt], acc[mt][nt], 0, 0, 0);
    }
    __syncthreads();
    const float c = 0.08838834764831845f; // 1/sqrt(128)
    u16* xpb = xp + (size_t)blockIdx.x * 128 * 128;
#pragma unroll
    for (int mt = 0; mt < 2; mt++){
#pragma unroll
        for (int r = 0; r < 4; r++){
            int t = 32*w + mt*16 + q*4 + r;
            float hs = 0.5f * sql[t];
#pragma unroll
            for (int nt = 0; nt < 8; nt++){
                int f = nt*16 + m;
                xpb[(size_t)t*128 + f] = f2b(__expf(fminf(acc[mt][nt][r] - hs, 60.f)) * c);
            }
        }
    }
}

// ---------- k path: featmap + per-chunk KV summary fused ----------
// One block = one (bh, chunk): computes kp = phi(k), S^T[d][f] = V^T.kp (MFMA), z = colsum(kp).
struct FM1 { u16 Xl[128][72]; u16 Wft[128][72]; };
union  FMU { FM1 p1; u16 Kpt[128][136]; };
__global__ __launch_bounds__(256) void featmap_sum(const u16* __restrict__ kh, const float* __restrict__ Wf,
                                                   const u16* __restrict__ vh, u16* __restrict__ kp,
                                                   u16* __restrict__ Sa, float* __restrict__ zs)
{
    __shared__ FMU sm;
    __shared__ u16 Vt[64][136];
    __shared__ float sqp[128][8];
    __shared__ float sql[128];
    int blk = blockIdx.x, tid = threadIdx.x;
    int lane = tid & 63, w = tid >> 6;
    int m = lane & 15, q = lane >> 4;
    const u16* xb = kh + (size_t)blk * 128 * 64;
    const u16* vb = vh + (size_t)blk * 128 * 64;   // same (bh,chunk) flat layout
    // stage K-chunk + sq partials
#pragma unroll
    for (int it = 0; it < 4; it++){
        int idx = tid + 256*it;
        int row = idx >> 3, c8 = (idx & 7) * 8;
        uint4 v = *reinterpret_cast<const uint4*>(xb + (size_t)row*64 + c8);
        *reinterpret_cast<uint4*>(&sm.p1.Xl[row][c8]) = v;
        u32 ww[4] = {v.x, v.y, v.z, v.w};
        float s = 0.f;
#pragma unroll
        for (int j = 0; j < 4; j++){
            float a = b2f_lo(ww[j]), bb = b2f_hi(ww[j]);
            s += a*a + bb*bb;
        }
        sqp[row][idx & 7] = s;
    }
    // stage Wf^T
#pragma unroll
    for (int it = 0; it < 8; it++){
        int idx = tid + 256*it;
        int d = idx >> 5, f4 = (idx & 31) * 4;
        float4 v = *reinterpret_cast<const float4*>(Wf + d*128 + f4);
        sm.p1.Wft[f4+0][d] = f2b(v.x); sm.p1.Wft[f4+1][d] = f2b(v.y);
        sm.p1.Wft[f4+2][d] = f2b(v.z); sm.p1.Wft[f4+3][d] = f2b(v.w);
    }
    // stage V transposed
#pragma unroll
    for (int it = 0; it < 4; it++){
        int idx = tid + 256*it;
        int t = idx >> 3, d8 = (idx & 7)*8;
        uint4 v = *reinterpret_cast<const uint4*>(vb + (size_t)t*64 + d8);
        u32 ww[4] = {v.x, v.y, v.z, v.w};
#pragma unroll
        for (int j = 0; j < 4; j++){
            Vt[d8 + 2*j][t]     = (u16)(ww[j] & 0xFFFFu);
            Vt[d8 + 2*j + 1][t] = (u16)(ww[j] >> 16);
        }
    }
    __syncthreads();
    if (tid < 128){
        float s = 0.f;
#pragma unroll
        for (int j = 0; j < 8; j++) s += sqp[tid][j];
        sql[tid] = s;
    }
    // phi MFMA
    f32x4 acc[2][8] = {};
#pragma unroll
    for (int ks = 0; ks < 2; ks++){
        bf16x8 af[2], bf[8];
#pragma unroll
        for (int mt = 0; mt < 2; mt++)
            af[mt] = *reinterpret_cast<const bf16x8*>(&sm.p1.Xl[32*w + mt*16 + m][ks*32 + q*8]);
#pragma unroll
        for (int nt = 0; nt < 8; nt++)
            bf[nt] = *reinterpret_cast<const bf16x8*>(&sm.p1.Wft[nt*16 + m][ks*32 + q*8]);
#pragma unroll
        for (int mt = 0; mt < 2; mt++)
#pragma unroll
            for (int nt = 0; nt < 8; nt++)
                acc[mt][nt] = __builtin_amdgcn_mfma_f32_16x16x32_bf16(af[mt], bf[nt], acc[mt][nt], 0, 0, 0);
    }
    __syncthreads();   // Xl/Wft reads complete (region about to be overwritten), sql visible
    // epilogue: phi -> global kp AND transposed LDS Kpt[f][t]
    const float c = 0.08838834764831845f;
    u16* xpb = kp + (size_t)blk * 128 * 128;
#pragma unroll
    for (int mt = 0; mt < 2; mt++){
#pragma unroll
        for (int r = 0; r < 4; r++){
            int t = 32*w + mt*16 + q*4 + r;
            float hs = 0.5f * sql[t];
#pragma unroll
            for (int nt = 0; nt < 8; nt++){
                int f = nt*16 + m;
                u16 pv = f2b(__expf(fminf(acc[mt][nt][r] - hs, 60.f)) * c);
                xpb[(size_t)t*128 + f] = pv;
                sm.Kpt[f][t] = pv;
            }
        }
    }
    __syncthreads();   // Kpt ready
    // S^T = V^T . kp : A[d][t]=Vt, B[f][t]=Kpt ; wave w -> d rows [16w,16w+16)
    f32x4 acc2[8] = {};
#pragma unroll
    for (int ks = 0; ks < 4; ks++){
        bf16x8 af = *reinterpret_cast<const bf16x8*>(&Vt[16*w + m][ks*32 + q*8]);
        bf16x8 bf[8];
#pragma unroll
        for (int nt = 0; nt < 8; nt++)
            bf[nt] = *reinterpret_cast<const bf16x8*>(&sm.Kpt[nt*16 + m][ks*32 + q*8]);
#pragma unroll
        for (int nt = 0; nt < 8; nt++)
            acc2[nt] = __builtin_amdgcn_mfma_f32_16x16x32_bf16(af, bf[nt], acc2[nt], 0, 0, 0);
    }
    u16* Sb = Sa + (size_t)blk*8192;
#pragma unroll
    for (int nt = 0; nt < 8; nt++){
#pragma unroll
        for (int r = 0; r < 4; r++){
            int d = 16*w + q*4 + r;
            int f = nt*16 + m;
            Sb[(size_t)d*128 + f] = f2b(acc2[nt][r]);
        }
    }
    // z = colsum(kp) from Kpt rows (17-stride bank walk: 2-way, free)
    if (tid < 128){
        float z = 0.f;
#pragma unroll
        for (int t = 0; t < 128; t++) z += b2f(sm.Kpt[tid][t]);
        zs[(size_t)blk*128 + tid] = z;
    }
}

// ---------- exclusive prefix over the 16 chunks (per bh), bf16 in/out ----------
__global__ __launch_bounds__(256) void prefix_chunks(const u16* __restrict__ Sa, u16* __restrict__ Sb,
                                                     float* __restrict__ zs)
{
    int bh = blockIdx.x, seg = blockIdx.y, tid = threadIdx.x;
    const u16* src = Sa + (size_t)bh*16*8192;
    u16*       dst = Sb + (size_t)bh*16*8192;
#pragma unroll
    for (int it = 0; it < 4; it++){
        int e = seg*1024 + it*256 + tid;
        float run = 0.f;
#pragma unroll
        for (int c = 0; c < 16; c++){
            float v = b2f(src[(size_t)c*8192 + e]);
            dst[(size_t)c*8192 + e] = f2b(run);
            run += v;
        }
    }
    if (seg == 0 && tid < 128){
        float run = 0.f; float* zp = zs + (size_t)bh*16*128 + tid;
#pragma unroll
        for (int c = 0; c < 16; c++){ float v = zp[c*128]; zp[c*128] = run; run += v; }
    }
}

// ---------- per-chunk output via MFMA; denominator fused as extra MFMA B-tiles ----------
__global__ __launch_bounds__(256) void chunk_out(const u16* __restrict__ qp, const u16* __restrict__ kp,
                                                 const u16* __restrict__ vh, const u16* __restrict__ St,
                                                 const float* __restrict__ zs, u16* __restrict__ y2d)
{
    __shared__ u16 P[128][136];
    __shared__ u16 Vt[64][136];
    __shared__ u16 zl[128];
    int blk = blockIdx.x, tid = threadIdx.x;
    int lane = tid & 63, w = tid >> 6;
    int m = lane & 15, q = lane >> 4;
    int bh = blk >> 4, c = blk & 15;
    int b = bh >> 4, h = bh & 15, t0 = c*128;
    const u16* qpb = qp + ((size_t)bh*2048 + t0)*128;
    const u16* kpb = kp + ((size_t)bh*2048 + t0)*128;
    const u16* vb  = vh + ((size_t)bh*2048 + t0)*64;
    const u16* Stb = St + (size_t)blk*8192;

    if (tid < 128) zl[tid] = f2b(zs[(size_t)blk*128 + tid]);
#pragma unroll
    for (int it = 0; it < 4; it++){
        int idx = tid + 256*it;
        int t = idx >> 3, d8 = (idx & 7)*8;
        uint4 v = *reinterpret_cast<const uint4*>(&vb[(size_t)t*64 + d8]);
        u32 ww[4] = {v.x, v.y, v.z, v.w};
#pragma unroll
        for (int j = 0; j < 4; j++){
            Vt[d8 + 2*j][t]     = (u16)(ww[j] & 0xFFFFu);
            Vt[d8 + 2*j + 1][t] = (u16)(ww[j] >> 16);
        }
    }
    {
        int row = tid >> 1, half = tid & 1;
        int i = row >> 4;
        for (int s2 = 16*(i + 1) + half*2; s2 < 128; s2 += 4)
            *reinterpret_cast<u32*>(&P[row][s2]) = 0;
    }
    {
        static const unsigned char TIa[36] = {0,1,1,2,2,2,3,3,3,3,4,4,4,4,4,
                                              5,5,5,5,5,5,6,6,6,6,6,6,6,7,7,7,7,7,7,7,7};
        static const unsigned char TJa[36] = {0,0,1,0,1,2,0,1,2,3,0,1,2,3,4,
                                              0,1,2,3,4,5,0,1,2,3,4,5,6,0,1,2,3,4,5,6,7};
        for (int idx = w; idx < 36; idx += 4){
            int i = TIa[idx], j = TJa[idx];
            f32x4 a = {};
            const u16* arow = qpb + (size_t)(i*16 + m)*128 + q*8;
            const u16* brow = kpb + (size_t)(j*16 + m)*128 + q*8;
#pragma unroll
            for (int ks = 0; ks < 4; ks++){
                bf16x8 af = *reinterpret_cast<const bf16x8*>(arow + ks*32);
                bf16x8 bf = *reinterpret_cast<const bf16x8*>(brow + ks*32);
                a = __builtin_amdgcn_mfma_f32_16x16x32_bf16(af, bf, a, 0, 0, 0);
            }
            int scol = j*16 + m;
#pragma unroll
            for (int r = 0; r < 4; r++){
                int trow = i*16 + q*4 + r;
                P[trow][scol] = (scol <= trow) ? f2b(a[r]) : (u16)0;
            }
        }
    }
    __syncthreads();
    f32x4 acc[2][4] = {};
    f32x4 accd[2] = {};
    bf16x8 ones;
#pragma unroll
    for (int i = 0; i < 8; i++) ones[i] = (__bf16)1.0f;
    for (int ks = 0; ks <= w; ks++){
        bf16x8 af[2], bf4[4];
#pragma unroll
        for (int mt = 0; mt < 2; mt++)
            af[mt] = *reinterpret_cast<const bf16x8*>(&P[32*w + mt*16 + m][ks*32 + q*8]);
#pragma unroll
        for (int nt = 0; nt < 4; nt++)
            bf4[nt] = *reinterpret_cast<const bf16x8*>(&Vt[nt*16 + m][ks*32 + q*8]);
#pragma unroll
        for (int mt = 0; mt < 2; mt++){
#pragma unroll
            for (int nt = 0; nt < 4; nt++)
                acc[mt][nt] = __builtin_amdgcn_mfma_f32_16x16x32_bf16(af[mt], bf4[nt], acc[mt][nt], 0, 0, 0);
            accd[mt] = __builtin_amdgcn_mfma_f32_16x16x32_bf16(af[mt], ones, accd[mt], 0, 0, 0);
        }
    }
#pragma unroll
    for (int ks = 0; ks < 4; ks++){
        bf16x8 af[2], bf4[4];
        bf16x8 zf = *reinterpret_cast<const bf16x8*>(&zl[ks*32 + q*8]);
#pragma unroll
        for (int mt = 0; mt < 2; mt++)
            af[mt] = *reinterpret_cast<const bf16x8*>(qpb + (size_t)(32*w + mt*16 + m)*128 + ks*32 + q*8);
#pragma unroll
        for (int nt = 0; nt < 4; nt++)
            bf4[nt] = *reinterpret_cast<const bf16x8*>(Stb + (size_t)(nt*16 + m)*128 + ks*32 + q*8);
#pragma unroll
        for (int mt = 0; mt < 2; mt++){
#pragma unroll
            for (int nt = 0; nt < 4; nt++)
                acc[mt][nt] = __builtin_amdgcn_mfma_f32_16x16x32_bf16(af[mt], bf4[nt], acc[mt][nt], 0, 0, 0);
            accd[mt] = __builtin_amdgcn_mfma_f32_16x16x32_bf16(af[mt], zf, accd[mt], 0, 0, 0);
        }
    }
#pragma unroll
    for (int mt = 0; mt < 2; mt++){
#pragma unroll
        for (int nt = 0; nt < 4; nt++){
#pragma unroll
            for (int r = 0; r < 4; r++){
                int t = 32*w + mt*16 + q*4 + r;
                int d = nt*16 + m;
                float den = accd[mt][r] + 1e-6f;
                y2d[((size_t)b*2048 + t0 + t)*1024 + h*64 + d] = f2b(acc[mt][nt][r] / den);
            }
        }
    }
}

extern "C" void kernel_launch(void* const* d_in, const int* in_sizes, int n_in,
                              void* d_out, int out_size, void* d_ws, size_t ws_size,
                              hipStream_t stream)
{
    (void)in_sizes; (void)n_in; (void)out_size; (void)ws_size;
    const float* x  = (const float*)d_in[0];
    const float* Wq = (const float*)d_in[1];
    const float* Wk = (const float*)d_in[2];
    const float* Wv = (const float*)d_in[3];
    const float* Wo = (const float*)d_in[4];
    const float* Wf = (const float*)d_in[5];
    float* out = (float*)d_out;
    char* ws = (char*)d_ws;

    // workspace layout (lifetime-aliased, ~136.5 MiB)
    u16*   xh    = (u16*)  (ws + 0);           // 16MB x bf16 (dead after QKV gemm)
    u16*   Sa    = (u16*)  (ws + 0);           // alias xh: chunk S^T raw bf16
    u16*   qh    = (u16*)  (ws + 16777216);    // 16MB (dead after featmap q)
    u16*   Sbp   = (u16*)  (ws + 16777216);    // alias qh: prefix S^T
    u16*   kh    = (u16*)  (ws + 33554432);    // 16MB (dead after featmap_sum)
    u16*   y2d   = (u16*)  (ws + 33554432);    // alias kh
    u16*   vh    = (u16*)  (ws + 50331648);    // 16MB
    u16*   qp    = (u16*)  (ws + 67108864);    // 32MB
    u16*   kp    = (u16*)  (ws + 100663296);   // 32MB
    u16*   WTqkv = (u16*)  (ws + 134217728);   // 6MB (3 x 1024x1024 bf16)
    u16*   WTo   = (u16*)  (ws + 140509184);   // 2MB
    float* zs    = (float*)(ws + 142606336);   // 0.5MB

    tobf16<<<4096, 256, 0, stream>>>(x, xh);
    transpose_all<<<dim3(16, 16, 4), 256, 0, stream>>>(Wq, Wk, Wv, Wo, WTqkv, WTo);

    // fused QKV: writes qh, kh, vh (contiguous 16MB blocks starting at qh)
    gemm_async<3><<<dim3(64, 24), 256, 0, stream>>>(xh, WTqkv, nullptr, qh);

    featmap_mfma<<<1024, 256, 0, stream>>>(qh, Wf, qp);
    featmap_sum<<<1024, 256, 0, stream>>>(kh, Wf, vh, kp, Sa, zs);

    prefix_chunks<<<dim3(64, 8), 256, 0, stream>>>(Sa, Sbp, zs);
    chunk_out<<<1024, 256, 0, stream>>>(qp, kp, vh, Sbp, zs, y2d);

    gemm_async<2><<<dim3(64, 8), 256, 0, stream>>>(y2d, WTo, out, nullptr);
}